// Round 1
// 410.861 us; speedup vs baseline: 1.1139x; 1.1139x over previous
//
#include <hip/hip_runtime.h>
#include <math.h>

// GCN via CSR gather. CSR(dst) built with a two-level binned counting sort where
// node degrees are derived INSIDE the partition sort (lsortA LDS histogram) --
// no global deg atomics. All scattered writes stay in block-private windows
// (R4-R6: device-wide scattered stores cost a full 64B line each).
// 3x (register-tiled GEMM[+fused relu] -> gather-agg) -> mean-pool -> head -> softmax.
// h is bf16.
// Gather v6 (this round): v5 was latency-bound (VALU 39%, HBM 23%, nothing
// saturated; 3.2 TB/s random-row throughput => ~20 lines in flight/CU). New
// layout: lane j = (edge-slot g=j>>3, feat-block f=j&7); per-lane dwordx4 row
// loads -> 8 edges per VMEM instruction, no readfirstlane chain; stride-32
// edge loop (4 row-load instrs in flight/wave); predication clamps to end-1
// (all overflow groups collapse to one line). shfl_xor(8/16/32) reduction,
// g==0 lanes store 2x float4.
// GEMM register pressure: R13 showed auto-unrolled k-loop -> 236 VGPR / 9.7% occ;
// R14 showed __launch_bounds__(256,4) forces SPILLS (547MB scratch writes, 2.6x
// slower). Fix at source: #pragma unroll 1 on the k-loop (live set ~70-90 VGPR),
// NO launch-bounds cap.
// N=100000 nodes, E=1.6M edges (+N self-loops folded into gather init), nhid=64.

__device__ __forceinline__ unsigned short f2bf(float f) {
    unsigned int u = __float_as_uint(f);
    u += 0x7fffu + ((u >> 16) & 1u);   // round-to-nearest-even
    return (unsigned short)(u >> 16);
}
__device__ __forceinline__ float bf2f(unsigned short u) {
    return __uint_as_float((unsigned int)u << 16);
}
__device__ __forceinline__ float bflo(unsigned int u) {
    return __uint_as_float(u << 16);
}
__device__ __forceinline__ float bfhi(unsigned int u) {
    return __uint_as_float(u & 0xffff0000u);
}

__global__ void zero_kernel(float* __restrict__ a, int n) {
    int i = blockIdx.x * 256 + threadIdx.x;
    if (i < n) a[i] = 0.f;
}

// ---- binned counting sort: partition = dst>>9 (512 nodes), P<=256, 256 chunks ----

__global__ __launch_bounds__(256) void hist_kernel(const int* __restrict__ dst,
                                                   int* __restrict__ counts,
                                                   int E, int P, int C) {
    __shared__ int hist[256];
    int t = threadIdx.x, b = blockIdx.x;
    if (t < P) hist[t] = 0;
    __syncthreads();
    int beg = b * C, end = min(E, beg + C);
    for (int e = beg + t; e < end; e += 256)
        atomicAdd(&hist[dst[e] >> 9], 1);
    __syncthreads();
    if (t < P) counts[t * 256 + b] = hist[t];
}

__global__ __launch_bounds__(256) void pscan_kernel(const int* __restrict__ counts,
                                                    int* __restrict__ pbase,
                                                    int* __restrict__ rowptr,
                                                    int P, int N) {
    __shared__ int s[256];
    int t = threadIdx.x;
    int v = 0;
    if (t < P)
        for (int b = 0; b < 256; ++b) v += counts[t * 256 + b];
    s[t] = v;
    __syncthreads();
    for (int off = 1; off < 256; off <<= 1) {
        int u = (t >= off) ? s[t - off] : 0;
        __syncthreads();
        s[t] += u;
        __syncthreads();
    }
    if (t < P) pbase[t] = s[t] - v;
    if (t == 255) { pbase[P] = s[255]; rowptr[N] = s[255]; }
}

__global__ __launch_bounds__(256) void offs_kernel(const int* __restrict__ counts,
                                                   const int* __restrict__ pbase,
                                                   int* __restrict__ offs) {
    __shared__ int s[256];
    int t = threadIdx.x, p = blockIdx.x;
    int v = counts[p * 256 + t];
    s[t] = v;
    __syncthreads();
    for (int off = 1; off < 256; off <<= 1) {
        int u = (t >= off) ? s[t - off] : 0;
        __syncthreads();
        s[t] += u;
        __syncthreads();
    }
    offs[p * 256 + t] = pbase[p] + s[t] - v;
}

__global__ __launch_bounds__(256) void bin_kernel(const int* __restrict__ src,
                                                  const int* __restrict__ dst,
                                                  const int* __restrict__ offs,
                                                  unsigned int* __restrict__ binned,
                                                  int E, int P, int C) {
    __shared__ int cur[256];
    int t = threadIdx.x, b = blockIdx.x;
    if (t < P) cur[t] = offs[t * 256 + b];
    __syncthreads();
    int beg = b * C, end = min(E, beg + C);
    for (int e = beg + t; e < end; e += 256) {
        int d = dst[e], s = src[e];
        int pos = atomicAdd(&cur[d >> 9], 1);
        binned[pos] = ((unsigned int)s << 9) | (unsigned int)(d & 511);
    }
}

__global__ __launch_bounds__(512) void lsortA_kernel(const unsigned int* __restrict__ binned,
                                                     const int* __restrict__ pbase,
                                                     int* __restrict__ rowptr,
                                                     float* __restrict__ dinv, int N) {
    __shared__ int ldeg[512];
    __shared__ int s[512];
    int t = threadIdx.x, p = blockIdx.x;
    int lo = p << 9;
    ldeg[t] = 0;
    __syncthreads();
    int eBeg = pbase[p], eEnd = pbase[p + 1];
    for (int j = eBeg + t; j < eEnd; j += 512)
        atomicAdd(&ldeg[binned[j] & 511u], 1);
    __syncthreads();
    int v = ldeg[t];
    s[t] = v;
    __syncthreads();
    for (int off = 1; off < 512; off <<= 1) {
        int u = (t >= off) ? s[t - off] : 0;
        __syncthreads();
        s[t] += u;
        __syncthreads();
    }
    if (lo + t < N) {
        rowptr[lo + t] = eBeg + s[t] - v;
        dinv[lo + t] = rsqrtf((float)(v + 1));
    }
}

__global__ __launch_bounds__(256) void lsortB_kernel(const unsigned int* __restrict__ binned,
                                                     const int* __restrict__ pbase,
                                                     const int* __restrict__ rowptr,
                                                     const float* __restrict__ dinv,
                                                     float2* __restrict__ csrw, int N) {
    __shared__ int cur[512];
    __shared__ float sdi[512];
    int t = threadIdx.x, p = blockIdx.x;
    int lo = p << 9, hi = min(N, lo + 512);
    for (int i = t; i < hi - lo; i += 256) {
        cur[i] = rowptr[lo + i];
        sdi[i] = dinv[lo + i];
    }
    __syncthreads();
    int eBeg = pbase[p], eEnd = pbase[p + 1];
    for (int j = eBeg + t; j < eEnd; j += 256) {
        unsigned int v = binned[j];
        int s = (int)(v >> 9);
        int dl = (int)(v & 511u);
        int pos = atomicAdd(&cur[dl], 1);
        csrw[pos] = make_float2(__int_as_float(s << 7), dinv[s] * sdi[dl]);
    }
}

// H[N,64](bf16) = relu?(X)[N,FIN](fp32) @ W[FIN,64]. Register-tiled: 64x64 tile per
// block, 256 threads x 4x4 outputs. sX leading dim padded +4. fp32 acc, bf16 store.
// k-loop pinned at unroll 1: live set = acc16+xr16+wr16 (~90 VGPR), no spills.
template <int FIN, bool RELU>
__global__ __launch_bounds__(256) void gemm_kernel(const float* __restrict__ X,
                                                   const float* __restrict__ W,
                                                   unsigned short* __restrict__ H, int N) {
    constexpr int FINP = FIN + 4;
    __shared__ float sW[FIN * 64];
    __shared__ float sX[64 * FINP];
    int tid = threadIdx.x;
    for (int i = tid * 4; i < FIN * 64; i += 1024)
        *(float4*)&sW[i] = *(const float4*)&W[i];
    int rowBase = blockIdx.x * 64;
    for (int i = tid * 4; i < 64 * FIN; i += 1024) {
        int r = i / FIN, c = i - r * FIN;
        int gr = rowBase + r;
        float4 v = make_float4(0.f, 0.f, 0.f, 0.f);
        if (gr < N) {
            v = *(const float4*)&X[(long)gr * FIN + c];
            if (RELU) {
                v.x = fmaxf(v.x, 0.f); v.y = fmaxf(v.y, 0.f);
                v.z = fmaxf(v.z, 0.f); v.w = fmaxf(v.w, 0.f);
            }
        }
        *(float4*)&sX[r * FINP + c] = v;
    }
    __syncthreads();
    int tx = tid & 15;
    int ty = tid >> 4;
    float acc[4][4];
#pragma unroll
    for (int rr = 0; rr < 4; ++rr)
#pragma unroll
        for (int cc = 0; cc < 4; ++cc) acc[rr][cc] = 0.f;
#pragma unroll 1
    for (int k = 0; k < FIN; k += 4) {
        float xr[4][4], wr[4][4];
#pragma unroll
        for (int rr = 0; rr < 4; ++rr)
            *(float4*)xr[rr] = *(const float4*)&sX[(ty + 16 * rr) * FINP + k];
#pragma unroll
        for (int kk = 0; kk < 4; ++kk)
            *(float4*)wr[kk] = *(const float4*)&sW[(k + kk) * 64 + 4 * tx];
#pragma unroll
        for (int rr = 0; rr < 4; ++rr)
#pragma unroll
            for (int kk = 0; kk < 4; ++kk)
#pragma unroll
                for (int cc = 0; cc < 4; ++cc)
                    acc[rr][cc] = fmaf(xr[rr][kk], wr[kk][cc], acc[rr][cc]);
    }
#pragma unroll
    for (int rr = 0; rr < 4; ++rr) {
        int gr = rowBase + ty + 16 * rr;
        if (gr < N) {
            ushort4 o;
            o.x = f2bf(acc[rr][0]); o.y = f2bf(acc[rr][1]);
            o.z = f2bf(acc[rr][2]); o.w = f2bf(acc[rr][3]);
            *(ushort4*)&H[(long)gr * 64 + 4 * tx] = o;
        }
    }
}

// Gather v6: one wave per dst node. lane j: edge-slot g=j>>3, feat-block f=j&7.
// Per iteration: 32 edges = 4x {csrw dwordx2 (coalesced 64B) + h dwordx4 (8
// random 128B rows / instruction)}. No readfirstlane; per-lane addresses.
// Predication clamps idx to end-1 (overflow groups collapse onto one row -> one
// extra line). Poisson(16) degrees => ~1 iteration/node. Epilogue: shfl_xor
// 8/16/32 reduction over edge-groups; g==0 lanes write 2x float4 (256B/node).
__global__ __launch_bounds__(256) void gather_kernel(const float2* __restrict__ csrw,
                                                     const int* __restrict__ rowptr,
                                                     const unsigned short* __restrict__ h,
                                                     const float* __restrict__ dinv,
                                                     const float* __restrict__ b,
                                                     float* __restrict__ agg, int N) {
    int node = (blockIdx.x * 256 + threadIdx.x) >> 6;
    int lane = threadIdx.x & 63;
    if (node >= N) return;
    int g = lane >> 3;          // edge slot 0..7
    int f = lane & 7;           // 16B feature chunk 0..7
    int fo = f * 16;            // byte offset inside a 128B h-row
    int beg = rowptr[node], end = rowptr[node + 1];
    float di = dinv[node];

    float acc[8];
#pragma unroll
    for (int k = 0; k < 8; ++k) acc[k] = 0.f;

    // self-loop + bias once (group 0 only; reduction sums groups)
    if (g == 0) {
        uint4 us = *(const uint4*)((const char*)h + ((size_t)node << 7) + fo);
        float s2 = di * di;
        float4 bv0 = *(const float4*)&b[f * 8];
        float4 bv1 = *(const float4*)&b[f * 8 + 4];
        acc[0] = fmaf(s2, bflo(us.x), bv0.x);
        acc[1] = fmaf(s2, bfhi(us.x), bv0.y);
        acc[2] = fmaf(s2, bflo(us.y), bv0.z);
        acc[3] = fmaf(s2, bfhi(us.y), bv0.w);
        acc[4] = fmaf(s2, bflo(us.z), bv1.x);
        acc[5] = fmaf(s2, bfhi(us.z), bv1.y);
        acc[6] = fmaf(s2, bflo(us.w), bv1.z);
        acc[7] = fmaf(s2, bfhi(us.w), bv1.w);
    }

    const char* hb = (const char*)h;
    for (int e = beg; e < end; e += 32) {
        float2 c[4];
        float w[4];
#pragma unroll
        for (int q = 0; q < 4; ++q) {
            int idx = e + 8 * q + g;
            c[q] = csrw[idx < end ? idx : end - 1];
            w[q] = idx < end ? 1.f : 0.f;
        }
        uint4 u[4];
#pragma unroll
        for (int q = 0; q < 4; ++q)
            u[q] = *(const uint4*)(hb + __float_as_int(c[q].x) + fo);
#pragma unroll
        for (int q = 0; q < 4; ++q) {
            float wq = w[q] * c[q].y;
            acc[0] = fmaf(wq, bflo(u[q].x), acc[0]);
            acc[1] = fmaf(wq, bfhi(u[q].x), acc[1]);
            acc[2] = fmaf(wq, bflo(u[q].y), acc[2]);
            acc[3] = fmaf(wq, bfhi(u[q].y), acc[3]);
            acc[4] = fmaf(wq, bflo(u[q].z), acc[4]);
            acc[5] = fmaf(wq, bfhi(u[q].z), acc[5]);
            acc[6] = fmaf(wq, bflo(u[q].w), acc[6]);
            acc[7] = fmaf(wq, bfhi(u[q].w), acc[7]);
        }
    }

    // reduce across the 8 edge-groups (lanes j, j^8, j^16, j^32 share f)
#pragma unroll
    for (int k = 0; k < 8; ++k) {
        float v = acc[k];
        v += __shfl_xor(v, 8);
        v += __shfl_xor(v, 16);
        v += __shfl_xor(v, 32);
        acc[k] = v;
    }
    if (g == 0) {
        float* ap = &agg[((size_t)node << 6) + f * 8];
        *(float4*)ap = make_float4(acc[0], acc[1], acc[2], acc[3]);
        *(float4*)(ap + 4) = make_float4(acc[4], acc[5], acc[6], acc[7]);
    }
}

// batch is sorted: one WAVE per 64 contiguous nodes (lane = col), running accumulation
// with flush on graph change; col==0 lane flushes run-length counts; fused relu.
__global__ __launch_bounds__(256) void pool_kernel(const float* __restrict__ h,
                                                   const int* __restrict__ batch,
                                                   float* __restrict__ sums,
                                                   float* __restrict__ cnts, int N) {
    int col = threadIdx.x & 63;
    int wave = threadIdx.x >> 6;
    int base = blockIdx.x * 256 + wave * 64;
    float acc = 0.f, cnt = 0.f;
    int curg = -1;
    for (int j = 0; j < 64; ++j) {
        int node = base + j;
        if (node >= N) break;
        int g = batch[node];
        if (g != curg) {
            if (curg >= 0) {
                atomicAdd(&sums[curg * 64 + col], acc);
                if (col == 0) atomicAdd(&cnts[curg], cnt);
            }
            acc = 0.f; cnt = 0.f;
            curg = g;
        }
        acc += fmaxf(h[(long)node * 64 + col], 0.f);
        cnt += 1.f;
    }
    if (curg >= 0) {
        atomicAdd(&sums[curg * 64 + col], acc);
        if (col == 0) atomicAdd(&cnts[curg], cnt);
    }
}

// One thread per graph: pooled = sums/cnt, logits = pooled @ Wl + bl, softmax.
__global__ void final_kernel(const float* __restrict__ sums, const float* __restrict__ cnts,
                             const float* __restrict__ Wl, const float* __restrict__ bl,
                             float* __restrict__ out, int G) {
    int g = blockIdx.x * blockDim.x + threadIdx.x;
    if (g >= G) return;
    float inv = 1.0f / fmaxf(cnts[g], 1.0f);
    float logits[10];
#pragma unroll
    for (int k = 0; k < 10; ++k) logits[k] = bl[k];
    for (int c = 0; c < 64; ++c) {
        float p = sums[g * 64 + c] * inv;
#pragma unroll
        for (int k = 0; k < 10; ++k) logits[k] = fmaf(p, Wl[c * 10 + k], logits[k]);
    }
    float m = logits[0];
#pragma unroll
    for (int k = 1; k < 10; ++k) m = fmaxf(m, logits[k]);
    float se = 0.f;
#pragma unroll
    for (int k = 0; k < 10; ++k) { logits[k] = expf(logits[k] - m); se += logits[k]; }
    float is = 1.0f / se;
#pragma unroll
    for (int k = 0; k < 10; ++k) out[g * 10 + k] = logits[k] * is;
}

extern "C" void kernel_launch(void* const* d_in, const int* in_sizes, int n_in,
                              void* d_out, int out_size, void* d_ws, size_t ws_size,
                              hipStream_t stream) {
    const float* x    = (const float*)d_in[0];
    const int* edges  = (const int*)d_in[1];
    const int* batch  = (const int*)d_in[2];
    const float* W1   = (const float*)d_in[3];
    const float* b1   = (const float*)d_in[4];
    const float* W2   = (const float*)d_in[5];
    const float* b2   = (const float*)d_in[6];
    const float* W3   = (const float*)d_in[7];
    const float* b3   = (const float*)d_in[8];
    const float* Wl   = (const float*)d_in[9];
    const float* bl   = (const float*)d_in[10];

    const int N = in_sizes[0] / 128;   // 100000
    const int E = in_sizes[1] / 2;     // 1600000
    const int G = out_size / 10;       // 64
    const int* src = edges;
    const int* dst = edges + E;

    float* ws     = (float*)d_ws;
    unsigned short* h = (unsigned short*)ws;      // N*64 bf16 (slot reserves N*64 floats)
    float* agg    = ws + (size_t)N * 64;          // N*64 fp32
    unsigned int* binned = (unsigned int*)ws;     // E uint ALIASES h slot: dead before gemm1
    float2* csrw  = (float2*)(ws + (size_t)2 * N * 64);  // E float2 {src_byte_off, w}
    float* dinv   = ws + (size_t)2 * N * 64 + (size_t)2 * E;  // N
    int*   rowptr = (int*)(dinv + N);             // N+1
    int*   counts = rowptr + N + 1;               // 256*256
    int*   offs   = counts + 256 * 256;           // 256*256
    int*   pbase  = offs + 256 * 256;             // P+1 <= 257
    float* sums   = (float*)(pbase + 257);        // G*64
    float* cnts   = sums + (size_t)G * 64;        // G

    const int gemmGrid = (N + 63) / 64;
    const int gatherGrid = (N + 3) / 4;
    const int P = (N + 511) >> 9;                 // 196 partitions of 512 nodes
    const int C = (E + 255) / 256;                // edges per chunk (256 chunks)

    // binned counting sort -> rowptr/dinv (lsortA) + csrw {src_byte_off, w} (lsortB)
    hist_kernel<<<256, 256, 0, stream>>>(dst, counts, E, P, C);
    pscan_kernel<<<1, 256, 0, stream>>>(counts, pbase, rowptr, P, N);
    offs_kernel<<<P, 256, 0, stream>>>(counts, pbase, offs);
    bin_kernel<<<256, 256, 0, stream>>>(src, dst, offs, binned, E, P, C);
    lsortA_kernel<<<P, 512, 0, stream>>>(binned, pbase, rowptr, dinv, N);
    lsortB_kernel<<<P, 256, 0, stream>>>(binned, pbase, rowptr, dinv, csrw, N);

    // layer 1: x[N,128] @ W1 -> h bf16 (overwrites binned; build complete); gather
    gemm_kernel<128, false><<<gemmGrid, 256, 0, stream>>>(x, W1, h, N);
    gather_kernel<<<gatherGrid, 256, 0, stream>>>(csrw, rowptr, h, dinv, b1, agg, N);

    // layer 2 (relu of layer-1 output fused into gemm's X load)
    gemm_kernel<64, true><<<gemmGrid, 256, 0, stream>>>(agg, W2, h, N);
    gather_kernel<<<gatherGrid, 256, 0, stream>>>(csrw, rowptr, h, dinv, b2, agg, N);

    // layer 3
    gemm_kernel<64, true><<<gemmGrid, 256, 0, stream>>>(agg, W3, h, N);
    gather_kernel<<<gatherGrid, 256, 0, stream>>>(csrw, rowptr, h, dinv, b3, agg, N);

    // mean-pool per graph (+count, +fused relu) + head + softmax
    zero_kernel<<<(G * 65 + 255) / 256, 256, 0, stream>>>(sums, G * 65);
    pool_kernel<<<(N + 255) / 256, 256, 0, stream>>>(agg, batch, sums, cnts, N);
    final_kernel<<<1, 64, 0, stream>>>(sums, cnts, Wl, bl, (float*)d_out, G);
}

// Round 2
// 393.814 us; speedup vs baseline: 1.1621x; 1.0433x over previous
//
#include <hip/hip_runtime.h>
#include <math.h>

// GCN via CSR gather. CSR(dst) built with a two-level binned counting sort where
// node degrees are derived INSIDE the partition sort (lsortA LDS histogram) --
// no global deg atomics. All scattered writes stay in block-private windows
// (R4-R6: device-wide scattered stores cost a full 64B line each).
// 3x (MFMA GEMM -> gather-agg[+relu,bf16]) -> mean-pool -> head -> softmax.
//
// Gather v6 (prev round): lane j = (edge-slot g=j>>3, feat-block f=j&7); per-lane
// dwordx4 row loads -> 8 edges per VMEM instruction; stride-32 edge loop;
// predication clamps to end-1; shfl_xor(8/16/32) reduction. 64.4 -> 47.5us.
// This round: relu folded into gather epilogue (every consumer wants relu(agg)),
// agg stored bf16 (halves gather writes + gemm2/3/pool reads).
//
// GEMM v2 (this round): fp32 vector GEMM was 48.5us at 16% occupancy (65KB LDS
// -> 2 blocks/CU) on the 157TF vector pipe. Replaced with LDS-free bf16 MFMA
// (16x16x32): A = Wt (ofeat x K, bf16, prepped once into dead counts region),
// B = X^T via direct 16B/lane global loads (lane&15 = node, 8 contiguous K).
// C/D layout per m89-verified col=lane&15,row=(lane>>4)*4+reg. K-slot map errors
// cancel (same assumed map for A and B => sum over permuted K).
// N=100000 nodes, E=1.6M edges (+N self-loops folded into gather init), nhid=64.

typedef __attribute__((ext_vector_type(8))) short bf16x8;
typedef __attribute__((ext_vector_type(4))) float f32x4;

__device__ __forceinline__ unsigned short f2bf(float f) {
    unsigned int u = __float_as_uint(f);
    u += 0x7fffu + ((u >> 16) & 1u);   // round-to-nearest-even
    return (unsigned short)(u >> 16);
}
__device__ __forceinline__ float bf2f(unsigned short u) {
    return __uint_as_float((unsigned int)u << 16);
}
__device__ __forceinline__ float bflo(unsigned int u) {
    return __uint_as_float(u << 16);
}
__device__ __forceinline__ float bfhi(unsigned int u) {
    return __uint_as_float(u & 0xffff0000u);
}

__global__ void zero_kernel(float* __restrict__ a, int n) {
    int i = blockIdx.x * 256 + threadIdx.x;
    if (i < n) a[i] = 0.f;
}

// ---- binned counting sort: partition = dst>>9 (512 nodes), P<=256, 256 chunks ----

__global__ __launch_bounds__(256) void hist_kernel(const int* __restrict__ dst,
                                                   int* __restrict__ counts,
                                                   int E, int P, int C) {
    __shared__ int hist[256];
    int t = threadIdx.x, b = blockIdx.x;
    if (t < P) hist[t] = 0;
    __syncthreads();
    int beg = b * C, end = min(E, beg + C);
    for (int e = beg + t; e < end; e += 256)
        atomicAdd(&hist[dst[e] >> 9], 1);
    __syncthreads();
    if (t < P) counts[t * 256 + b] = hist[t];
}

__global__ __launch_bounds__(256) void pscan_kernel(const int* __restrict__ counts,
                                                    int* __restrict__ pbase,
                                                    int* __restrict__ rowptr,
                                                    int P, int N) {
    __shared__ int s[256];
    int t = threadIdx.x;
    int v = 0;
    if (t < P)
        for (int b = 0; b < 256; ++b) v += counts[t * 256 + b];
    s[t] = v;
    __syncthreads();
    for (int off = 1; off < 256; off <<= 1) {
        int u = (t >= off) ? s[t - off] : 0;
        __syncthreads();
        s[t] += u;
        __syncthreads();
    }
    if (t < P) pbase[t] = s[t] - v;
    if (t == 255) { pbase[P] = s[255]; rowptr[N] = s[255]; }
}

__global__ __launch_bounds__(256) void offs_kernel(const int* __restrict__ counts,
                                                   const int* __restrict__ pbase,
                                                   int* __restrict__ offs) {
    __shared__ int s[256];
    int t = threadIdx.x, p = blockIdx.x;
    int v = counts[p * 256 + t];
    s[t] = v;
    __syncthreads();
    for (int off = 1; off < 256; off <<= 1) {
        int u = (t >= off) ? s[t - off] : 0;
        __syncthreads();
        s[t] += u;
        __syncthreads();
    }
    offs[p * 256 + t] = pbase[p] + s[t] - v;
}

__global__ __launch_bounds__(256) void bin_kernel(const int* __restrict__ src,
                                                  const int* __restrict__ dst,
                                                  const int* __restrict__ offs,
                                                  unsigned int* __restrict__ binned,
                                                  int E, int P, int C) {
    __shared__ int cur[256];
    int t = threadIdx.x, b = blockIdx.x;
    if (t < P) cur[t] = offs[t * 256 + b];
    __syncthreads();
    int beg = b * C, end = min(E, beg + C);
    for (int e = beg + t; e < end; e += 256) {
        int d = dst[e], s = src[e];
        int pos = atomicAdd(&cur[d >> 9], 1);
        binned[pos] = ((unsigned int)s << 9) | (unsigned int)(d & 511);
    }
}

__global__ __launch_bounds__(512) void lsortA_kernel(const unsigned int* __restrict__ binned,
                                                     const int* __restrict__ pbase,
                                                     int* __restrict__ rowptr,
                                                     float* __restrict__ dinv, int N) {
    __shared__ int ldeg[512];
    __shared__ int s[512];
    int t = threadIdx.x, p = blockIdx.x;
    int lo = p << 9;
    ldeg[t] = 0;
    __syncthreads();
    int eBeg = pbase[p], eEnd = pbase[p + 1];
    for (int j = eBeg + t; j < eEnd; j += 512)
        atomicAdd(&ldeg[binned[j] & 511u], 1);
    __syncthreads();
    int v = ldeg[t];
    s[t] = v;
    __syncthreads();
    for (int off = 1; off < 512; off <<= 1) {
        int u = (t >= off) ? s[t - off] : 0;
        __syncthreads();
        s[t] += u;
        __syncthreads();
    }
    if (lo + t < N) {
        rowptr[lo + t] = eBeg + s[t] - v;
        dinv[lo + t] = rsqrtf((float)(v + 1));
    }
}

__global__ __launch_bounds__(256) void lsortB_kernel(const unsigned int* __restrict__ binned,
                                                     const int* __restrict__ pbase,
                                                     const int* __restrict__ rowptr,
                                                     const float* __restrict__ dinv,
                                                     float2* __restrict__ csrw, int N) {
    __shared__ int cur[512];
    __shared__ float sdi[512];
    int t = threadIdx.x, p = blockIdx.x;
    int lo = p << 9, hi = min(N, lo + 512);
    for (int i = t; i < hi - lo; i += 256) {
        cur[i] = rowptr[lo + i];
        sdi[i] = dinv[lo + i];
    }
    __syncthreads();
    int eBeg = pbase[p], eEnd = pbase[p + 1];
    for (int j = eBeg + t; j < eEnd; j += 256) {
        unsigned int v = binned[j];
        int s = (int)(v >> 9);
        int dl = (int)(v & 511u);
        int pos = atomicAdd(&cur[dl], 1);
        csrw[pos] = make_float2(__int_as_float(s << 7), dinv[s] * sdi[dl]);
    }
}

// Wt[ofeat][k] bf16 <- W[k][ofeat] fp32. block 0: W1(K=128), 1: W2, 2: W3.
__global__ __launch_bounds__(256) void prepw_kernel(const float* __restrict__ W1,
                                                    const float* __restrict__ W2,
                                                    const float* __restrict__ W3,
                                                    unsigned short* __restrict__ Wt1,
                                                    unsigned short* __restrict__ Wt2,
                                                    unsigned short* __restrict__ Wt3) {
    int t = threadIdx.x, b = blockIdx.x;
    const float* W = (b == 0) ? W1 : ((b == 1) ? W2 : W3);
    unsigned short* Wt = (b == 0) ? Wt1 : ((b == 1) ? Wt2 : Wt3);
    int K = (b == 0) ? 128 : 64;
    int o = t & 63;
    for (int k = t >> 6; k < K; k += 4)
        Wt[o * K + k] = f2bf(W[k * 64 + o]);
}

// MFMA GEMM: H[N,64](bf16) = X[N,FIN] @ W[FIN,64].  D = A*B with A=Wt (M=ofeat,
// K), B=X^T (K, N=node). One wave = 16 nodes x 64 ofeats. No LDS, no barriers.
// A-frag: lane holds Wt[m*16+(l&15)][s*32+(l>>4)*8 ..+7] (16B load).
// B-frag: lane holds X[node=base+(l&15)][s*32+(l>>4)*8 ..+7] (16B load; fp32
// path converts 2x float4 -> bf16x8).  D: lane l reg r -> ofeat=m*16+(l>>4)*4+r,
// node=base+(l&15).
template <int FIN, bool F32IN>
__global__ __launch_bounds__(256) void gemm_mfma_kernel(const void* __restrict__ Xv,
                                                        const unsigned short* __restrict__ Wt,
                                                        unsigned short* __restrict__ H,
                                                        int N) {
    constexpr int KS = FIN / 32;
    int wave = threadIdx.x >> 6;
    int lane = threadIdx.x & 63;
    int r = lane & 15, g = lane >> 4;
    int node = blockIdx.x * 64 + wave * 16 + r;
    int nodeL = min(node, N - 1);

    bf16x8 afr[4][KS];
#pragma unroll
    for (int m = 0; m < 4; ++m)
#pragma unroll
        for (int s = 0; s < KS; ++s)
            afr[m][s] = *(const bf16x8*)&Wt[(m * 16 + r) * FIN + s * 32 + g * 8];

    f32x4 acc[4];
#pragma unroll
    for (int m = 0; m < 4; ++m) acc[m] = (f32x4){0.f, 0.f, 0.f, 0.f};

#pragma unroll
    for (int s = 0; s < KS; ++s) {
        bf16x8 bfr;
        if (F32IN) {
            const float* X = (const float*)Xv + (size_t)nodeL * FIN + s * 32 + g * 8;
            float4 lo = *(const float4*)X;
            float4 hi = *(const float4*)(X + 4);
            bfr[0] = (short)f2bf(lo.x); bfr[1] = (short)f2bf(lo.y);
            bfr[2] = (short)f2bf(lo.z); bfr[3] = (short)f2bf(lo.w);
            bfr[4] = (short)f2bf(hi.x); bfr[5] = (short)f2bf(hi.y);
            bfr[6] = (short)f2bf(hi.z); bfr[7] = (short)f2bf(hi.w);
        } else {
            bfr = *(const bf16x8*)((const unsigned short*)Xv + (size_t)nodeL * FIN + s * 32 + g * 8);
        }
#pragma unroll
        for (int m = 0; m < 4; ++m)
            acc[m] = __builtin_amdgcn_mfma_f32_16x16x32_bf16(afr[m][s], bfr, acc[m], 0, 0, 0);
    }

    if (node < N) {
#pragma unroll
        for (int m = 0; m < 4; ++m) {
            ushort4 o;
            o.x = f2bf(acc[m][0]); o.y = f2bf(acc[m][1]);
            o.z = f2bf(acc[m][2]); o.w = f2bf(acc[m][3]);
            *(ushort4*)&H[(size_t)node * 64 + m * 16 + g * 4] = o;
        }
    }
}

// Gather v6+relu/bf16: one wave per dst node. lane j: edge-slot g=j>>3, feat f=j&7.
// Per iteration: 32 edges = 4x {csrw dwordx2 + h dwordx4 (8 random 128B rows /
// instruction)}. Predication clamps idx to end-1. shfl_xor 8/16/32 reduction;
// relu in fp32; g==0 lanes write one 16B bf16 chunk (128B/node total).
__global__ __launch_bounds__(256) void gather_kernel(const float2* __restrict__ csrw,
                                                     const int* __restrict__ rowptr,
                                                     const unsigned short* __restrict__ h,
                                                     const float* __restrict__ dinv,
                                                     const float* __restrict__ b,
                                                     unsigned short* __restrict__ aggb, int N) {
    int node = (blockIdx.x * 256 + threadIdx.x) >> 6;
    int lane = threadIdx.x & 63;
    if (node >= N) return;
    int g = lane >> 3;          // edge slot 0..7
    int f = lane & 7;           // 16B feature chunk 0..7
    int fo = f * 16;            // byte offset inside a 128B h-row
    int beg = rowptr[node], end = rowptr[node + 1];
    float di = dinv[node];

    float acc[8];
#pragma unroll
    for (int k = 0; k < 8; ++k) acc[k] = 0.f;

    // self-loop + bias once (group 0 only; reduction sums groups)
    if (g == 0) {
        uint4 us = *(const uint4*)((const char*)h + ((size_t)node << 7) + fo);
        float s2 = di * di;
        float4 bv0 = *(const float4*)&b[f * 8];
        float4 bv1 = *(const float4*)&b[f * 8 + 4];
        acc[0] = fmaf(s2, bflo(us.x), bv0.x);
        acc[1] = fmaf(s2, bfhi(us.x), bv0.y);
        acc[2] = fmaf(s2, bflo(us.y), bv0.z);
        acc[3] = fmaf(s2, bfhi(us.y), bv0.w);
        acc[4] = fmaf(s2, bflo(us.z), bv1.x);
        acc[5] = fmaf(s2, bfhi(us.z), bv1.y);
        acc[6] = fmaf(s2, bflo(us.w), bv1.z);
        acc[7] = fmaf(s2, bfhi(us.w), bv1.w);
    }

    const char* hb = (const char*)h;
    for (int e = beg; e < end; e += 32) {
        float2 c[4];
        float w[4];
#pragma unroll
        for (int q = 0; q < 4; ++q) {
            int idx = e + 8 * q + g;
            c[q] = csrw[idx < end ? idx : end - 1];
            w[q] = idx < end ? 1.f : 0.f;
        }
        uint4 u[4];
#pragma unroll
        for (int q = 0; q < 4; ++q)
            u[q] = *(const uint4*)(hb + __float_as_int(c[q].x) + fo);
#pragma unroll
        for (int q = 0; q < 4; ++q) {
            float wq = w[q] * c[q].y;
            acc[0] = fmaf(wq, bflo(u[q].x), acc[0]);
            acc[1] = fmaf(wq, bfhi(u[q].x), acc[1]);
            acc[2] = fmaf(wq, bflo(u[q].y), acc[2]);
            acc[3] = fmaf(wq, bfhi(u[q].y), acc[3]);
            acc[4] = fmaf(wq, bflo(u[q].z), acc[4]);
            acc[5] = fmaf(wq, bfhi(u[q].z), acc[5]);
            acc[6] = fmaf(wq, bflo(u[q].w), acc[6]);
            acc[7] = fmaf(wq, bfhi(u[q].w), acc[7]);
        }
    }

    // reduce across the 8 edge-groups (lanes j, j^8, j^16, j^32 share f)
#pragma unroll
    for (int k = 0; k < 8; ++k) {
        float v = acc[k];
        v += __shfl_xor(v, 8);
        v += __shfl_xor(v, 16);
        v += __shfl_xor(v, 32);
        acc[k] = fmaxf(v, 0.f);   // relu folded: every consumer wants relu(agg)
    }
    if (g == 0) {
        uint4 o;
        o.x = ((unsigned)f2bf(acc[1]) << 16) | f2bf(acc[0]);
        o.y = ((unsigned)f2bf(acc[3]) << 16) | f2bf(acc[2]);
        o.z = ((unsigned)f2bf(acc[5]) << 16) | f2bf(acc[4]);
        o.w = ((unsigned)f2bf(acc[7]) << 16) | f2bf(acc[6]);
        *(uint4*)&aggb[((size_t)node << 6) + f * 8] = o;
    }
}

// batch is sorted: one WAVE per 64 contiguous nodes (lane = col), running accumulation
// with flush on graph change; col==0 lane flushes run-length counts. agg is bf16,
// already relu'd by gather.
__global__ __launch_bounds__(256) void pool_kernel(const unsigned short* __restrict__ hb,
                                                   const int* __restrict__ batch,
                                                   float* __restrict__ sums,
                                                   float* __restrict__ cnts, int N) {
    int col = threadIdx.x & 63;
    int wave = threadIdx.x >> 6;
    int base = blockIdx.x * 256 + wave * 64;
    float acc = 0.f, cnt = 0.f;
    int curg = -1;
    for (int j = 0; j < 64; ++j) {
        int node = base + j;
        if (node >= N) break;
        int g = batch[node];
        if (g != curg) {
            if (curg >= 0) {
                atomicAdd(&sums[curg * 64 + col], acc);
                if (col == 0) atomicAdd(&cnts[curg], cnt);
            }
            acc = 0.f; cnt = 0.f;
            curg = g;
        }
        acc += bf2f(hb[(size_t)node * 64 + col]);
        cnt += 1.f;
    }
    if (curg >= 0) {
        atomicAdd(&sums[curg * 64 + col], acc);
        if (col == 0) atomicAdd(&cnts[curg], cnt);
    }
}

// One thread per graph: pooled = sums/cnt, logits = pooled @ Wl + bl, softmax.
__global__ void final_kernel(const float* __restrict__ sums, const float* __restrict__ cnts,
                             const float* __restrict__ Wl, const float* __restrict__ bl,
                             float* __restrict__ out, int G) {
    int g = blockIdx.x * blockDim.x + threadIdx.x;
    if (g >= G) return;
    float inv = 1.0f / fmaxf(cnts[g], 1.0f);
    float logits[10];
#pragma unroll
    for (int k = 0; k < 10; ++k) logits[k] = bl[k];
    for (int c = 0; c < 64; ++c) {
        float p = sums[g * 64 + c] * inv;
#pragma unroll
        for (int k = 0; k < 10; ++k) logits[k] = fmaf(p, Wl[c * 10 + k], logits[k]);
    }
    float m = logits[0];
#pragma unroll
    for (int k = 1; k < 10; ++k) m = fmaxf(m, logits[k]);
    float se = 0.f;
#pragma unroll
    for (int k = 0; k < 10; ++k) { logits[k] = expf(logits[k] - m); se += logits[k]; }
    float is = 1.0f / se;
#pragma unroll
    for (int k = 0; k < 10; ++k) out[g * 10 + k] = logits[k] * is;
}

extern "C" void kernel_launch(void* const* d_in, const int* in_sizes, int n_in,
                              void* d_out, int out_size, void* d_ws, size_t ws_size,
                              hipStream_t stream) {
    const float* x    = (const float*)d_in[0];
    const int* edges  = (const int*)d_in[1];
    const int* batch  = (const int*)d_in[2];
    const float* W1   = (const float*)d_in[3];
    const float* b1   = (const float*)d_in[4];
    const float* W2   = (const float*)d_in[5];
    const float* b2   = (const float*)d_in[6];
    const float* W3   = (const float*)d_in[7];
    const float* b3   = (const float*)d_in[8];
    const float* Wl   = (const float*)d_in[9];
    const float* bl   = (const float*)d_in[10];

    const int N = in_sizes[0] / 128;   // 100000
    const int E = in_sizes[1] / 2;     // 1600000
    const int G = out_size / 10;       // 64
    const int* src = edges;
    const int* dst = edges + E;

    float* ws     = (float*)d_ws;
    unsigned short* h = (unsigned short*)ws;      // N*64 bf16 (slot reserves N*64 floats)
    unsigned short* aggb = (unsigned short*)(ws + (size_t)N * 64);  // N*64 bf16 (relu'd)
    unsigned int* binned = (unsigned int*)ws;     // E uint ALIASES h slot: dead before gemm1
    float2* csrw  = (float2*)(ws + (size_t)2 * N * 64);  // E float2 {src_byte_off, w}
    float* dinv   = ws + (size_t)2 * N * 64 + (size_t)2 * E;  // N
    int*   rowptr = (int*)(dinv + N);             // N+1
    int*   counts = rowptr + N + 1;               // 256*256
    int*   offs   = counts + 256 * 256;           // 256*256
    int*   pbase  = offs + 256 * 256;             // P+1 <= 257
    float* sums   = (float*)(pbase + 257);        // G*64
    float* cnts   = sums + (size_t)G * 64;        // G

    // Wt bf16 buffers carved from the counts region (dead after offs_kernel),
    // 16B-aligned (offset rounded to a multiple of 4 floats).
    size_t cntOff = (size_t)2 * N * 64 + (size_t)2 * E + N + (N + 1);
    size_t wtOff  = (cntOff + 3) & ~(size_t)3;
    unsigned short* Wt1 = (unsigned short*)(ws + wtOff);  // 64*128
    unsigned short* Wt2 = Wt1 + 64 * 128;                 // 64*64
    unsigned short* Wt3 = Wt2 + 64 * 64;                  // 64*64

    const int gemmGrid = (N + 63) / 64;
    const int gatherGrid = (N + 3) / 4;
    const int P = (N + 511) >> 9;                 // 196 partitions of 512 nodes
    const int C = (E + 255) / 256;                // edges per chunk (256 chunks)

    // binned counting sort -> rowptr/dinv (lsortA) + csrw {src_byte_off, w} (lsortB)
    hist_kernel<<<256, 256, 0, stream>>>(dst, counts, E, P, C);
    pscan_kernel<<<1, 256, 0, stream>>>(counts, pbase, rowptr, P, N);
    offs_kernel<<<P, 256, 0, stream>>>(counts, pbase, offs);
    prepw_kernel<<<3, 256, 0, stream>>>(W1, W2, W3, Wt1, Wt2, Wt3);  // counts now dead
    bin_kernel<<<256, 256, 0, stream>>>(src, dst, offs, binned, E, P, C);
    lsortA_kernel<<<P, 512, 0, stream>>>(binned, pbase, rowptr, dinv, N);
    lsortB_kernel<<<P, 256, 0, stream>>>(binned, pbase, rowptr, dinv, csrw, N);

    // layer 1: x[N,128] @ W1 -> h bf16 (overwrites binned; build complete); gather
    gemm_mfma_kernel<128, true><<<gemmGrid, 256, 0, stream>>>(x, Wt1, h, N);
    gather_kernel<<<gatherGrid, 256, 0, stream>>>(csrw, rowptr, h, dinv, b1, aggb, N);

    // layer 2 (aggb already relu'd bf16)
    gemm_mfma_kernel<64, false><<<gemmGrid, 256, 0, stream>>>(aggb, Wt2, h, N);
    gather_kernel<<<gatherGrid, 256, 0, stream>>>(csrw, rowptr, h, dinv, b2, aggb, N);

    // layer 3
    gemm_mfma_kernel<64, false><<<gemmGrid, 256, 0, stream>>>(aggb, Wt3, h, N);
    gather_kernel<<<gatherGrid, 256, 0, stream>>>(csrw, rowptr, h, dinv, b3, aggb, N);

    // mean-pool per graph (+count) + head + softmax
    zero_kernel<<<(G * 65 + 255) / 256, 256, 0, stream>>>(sums, G * 65);
    pool_kernel<<<(N + 255) / 256, 256, 0, stream>>>(aggb, batch, sums, cnts, N);
    final_kernel<<<1, 64, 0, stream>>>(sums, cnts, Wl, bl, (float*)d_out, G);
}

// Round 3
// 387.273 us; speedup vs baseline: 1.1817x; 1.0169x over previous
//
#include <hip/hip_runtime.h>
#include <math.h>

// GCN via CSR gather. CSR(dst) built with a two-level binned counting sort where
// node degrees are derived INSIDE the partition sort (lsortA LDS histogram).
// 3x (MFMA GEMM -> gather-agg[+relu,bf16]) -> mean-pool -> head -> softmax.
//
// Gather v7 (this round): v6 was VALU-bound (VALUBusy 70%) with 100% slot waste
// (stride-32 clamp over Poisson(16) degrees) + clamp cndmasks + self-loop branch.
// CSR is now PADDED to 8-edge alignment at build time with the self-loop folded
// in as a real edge ({node<<7, dinv^2}) and pads {0, 0.0} (row 0, weight 0).
// Gather runs fully-unguarded tiered chunks (32/16/8): no predication at all.
// Slots/node 32 -> 20.5 avg, per-slot VALU 23 -> 20, bias folded into epilogue.
// Build-side: lsortA computes align8(deg+1) spans + partition totals; pscan8
// (1 block) scans totals -> pbase8; lsortB fixes rowptr += pbase8, scatters,
// appends self edge, fills pads. binned/pbase stay REAL (unpadded).
//
// GEMM v2 (round 2): LDS-free bf16 MFMA 16x16x32, A=Wt (ofeat x K bf16), B=X^T
// direct 16B/lane loads. 48.5us fp32-vector -> off top-5. This round: X fp32->bf16
// cvt via +0x8000 round-half-up + v_perm_b32 pack (12 VALU per 8 vals, was 32).
// Gather v6 (round 1): lane j=(edge g=j>>3, feat16B f=j&7), dwordx4 row loads ->
// 8 edges per VMEM instr. 64.4 -> 47.5 -> 45.2us.
// N=100000 nodes, E=1.6M edges, nhid=64, Poisson(16) degrees.

typedef __attribute__((ext_vector_type(8))) short bf16x8;
typedef __attribute__((ext_vector_type(4))) float f32x4;

__device__ __forceinline__ unsigned short f2bf(float f) {
    unsigned int u = __float_as_uint(f);
    u += 0x7fffu + ((u >> 16) & 1u);   // round-to-nearest-even
    return (unsigned short)(u >> 16);
}
__device__ __forceinline__ float bf2f(unsigned short u) {
    return __uint_as_float((unsigned int)u << 16);
}
__device__ __forceinline__ float bflo(unsigned int u) {
    return __uint_as_float(u << 16);
}
__device__ __forceinline__ float bfhi(unsigned int u) {
    return __uint_as_float(u & 0xffff0000u);
}

// ---- binned counting sort: partition = dst>>9 (512 nodes), P<=256, 256 chunks ----
// hist fused: blocks 256..258 = W->Wt bf16 transpose; block 259 = zero sums/cnts.

__global__ __launch_bounds__(256) void hist_kernel(const int* __restrict__ dst,
                                                   int* __restrict__ counts,
                                                   int E, int P, int C,
                                                   const float* __restrict__ W1,
                                                   const float* __restrict__ W2,
                                                   const float* __restrict__ W3,
                                                   unsigned short* __restrict__ Wt1,
                                                   unsigned short* __restrict__ Wt2,
                                                   unsigned short* __restrict__ Wt3,
                                                   float* __restrict__ sums, int G) {
    int t = threadIdx.x, b = blockIdx.x;
    if (b >= 256) {
        int xb = b - 256;
        if (xb < 3) {           // prepw
            const float* W = (xb == 0) ? W1 : ((xb == 1) ? W2 : W3);
            unsigned short* Wt = (xb == 0) ? Wt1 : ((xb == 1) ? Wt2 : Wt3);
            int K = (xb == 0) ? 128 : 64;
            int o = t & 63;
            for (int k = t >> 6; k < K; k += 4)
                Wt[o * K + k] = f2bf(W[k * 64 + o]);
        } else {                // zero sums+cnts (G*65 floats)
            for (int i = t; i < G * 65; i += 256) sums[i] = 0.f;
        }
        return;
    }
    __shared__ int hist[256];
    if (t < P) hist[t] = 0;
    __syncthreads();
    int beg = b * C, end = min(E, beg + C);
    for (int e = beg + t; e < end; e += 256)
        atomicAdd(&hist[dst[e] >> 9], 1);
    __syncthreads();
    if (t < P) counts[t * 256 + b] = hist[t];
}

__global__ __launch_bounds__(256) void pscan_kernel(const int* __restrict__ counts,
                                                    int* __restrict__ pbase,
                                                    int P) {
    __shared__ int s[256];
    int t = threadIdx.x;
    int v = 0;
    if (t < P)
        for (int b = 0; b < 256; ++b) v += counts[t * 256 + b];
    s[t] = v;
    __syncthreads();
    for (int off = 1; off < 256; off <<= 1) {
        int u = (t >= off) ? s[t - off] : 0;
        __syncthreads();
        s[t] += u;
        __syncthreads();
    }
    if (t < P) pbase[t] = s[t] - v;
    if (t == 255) pbase[P] = s[255];
}

__global__ __launch_bounds__(256) void offs_kernel(const int* __restrict__ counts,
                                                   const int* __restrict__ pbase,
                                                   int* __restrict__ offs) {
    __shared__ int s[256];
    int t = threadIdx.x, p = blockIdx.x;
    int v = counts[p * 256 + t];
    s[t] = v;
    __syncthreads();
    for (int off = 1; off < 256; off <<= 1) {
        int u = (t >= off) ? s[t - off] : 0;
        __syncthreads();
        s[t] += u;
        __syncthreads();
    }
    offs[p * 256 + t] = pbase[p] + s[t] - v;
}

__global__ __launch_bounds__(256) void bin_kernel(const int* __restrict__ src,
                                                  const int* __restrict__ dst,
                                                  const int* __restrict__ offs,
                                                  unsigned int* __restrict__ binned,
                                                  int E, int P, int C) {
    __shared__ int cur[256];
    int t = threadIdx.x, b = blockIdx.x;
    if (t < P) cur[t] = offs[t * 256 + b];
    __syncthreads();
    int beg = b * C, end = min(E, beg + C);
    for (int e = beg + t; e < end; e += 256) {
        int d = dst[e], s = src[e];
        int pos = atomicAdd(&cur[d >> 9], 1);
        binned[pos] = ((unsigned int)s << 9) | (unsigned int)(d & 511);
    }
}

// Per-node real degree (LDS histogram) -> 8-aligned span align8(deg+1) (+1 = self
// loop). rowptr gets LOCAL aligned offsets; partTot8[p] = partition aligned total.
__global__ __launch_bounds__(512) void lsortA_kernel(const unsigned int* __restrict__ binned,
                                                     const int* __restrict__ pbase,
                                                     int* __restrict__ rowptr,
                                                     float* __restrict__ dinv,
                                                     int* __restrict__ partTot8, int N) {
    __shared__ int ldeg[512];
    __shared__ int s[512];
    int t = threadIdx.x, p = blockIdx.x;
    int lo = p << 9;
    ldeg[t] = 0;
    __syncthreads();
    int eBeg = pbase[p], eEnd = pbase[p + 1];
    for (int j = eBeg + t; j < eEnd; j += 512)
        atomicAdd(&ldeg[binned[j] & 511u], 1);
    __syncthreads();
    int real = ldeg[t];
    int a = (lo + t < N) ? ((real + 1 + 7) & ~7) : 0;   // +1 self, pad to 8
    s[t] = a;
    __syncthreads();
    for (int off = 1; off < 512; off <<= 1) {
        int u = (t >= off) ? s[t - off] : 0;
        __syncthreads();
        s[t] += u;
        __syncthreads();
    }
    if (lo + t < N) {
        rowptr[lo + t] = s[t] - a;                       // local aligned offset
        dinv[lo + t] = rsqrtf((float)(real + 1));
    }
    if (t == 511) partTot8[p] = s[511];
}

// 1 block: scan partition aligned totals -> pbase8; rowptr[N] = grand total.
__global__ __launch_bounds__(256) void pscan8_kernel(const int* __restrict__ partTot8,
                                                     int* __restrict__ pbase8,
                                                     int* __restrict__ rowptr,
                                                     int P, int N) {
    __shared__ int s[256];
    int t = threadIdx.x;
    int v = (t < P) ? partTot8[t] : 0;
    s[t] = v;
    __syncthreads();
    for (int off = 1; off < 256; off <<= 1) {
        int u = (t >= off) ? s[t - off] : 0;
        __syncthreads();
        s[t] += u;
        __syncthreads();
    }
    if (t < P) pbase8[t] = s[t] - v;
    if (t == 255) { pbase8[P] = s[255]; rowptr[N] = s[255]; }
}

// Fix rowptr to global aligned offsets, scatter real edges, append self edge,
// fill pads {0,0}. All scatter windows are block-private (LDS cursors).
__global__ __launch_bounds__(256) void lsortB_kernel(const unsigned int* __restrict__ binned,
                                                     const int* __restrict__ pbase,
                                                     const int* __restrict__ pbase8,
                                                     int* __restrict__ rowptr,
                                                     const float* __restrict__ dinv,
                                                     float2* __restrict__ csrw, int N) {
    __shared__ int srow[513];
    __shared__ int cur[512];
    __shared__ float sdi[512];
    int t = threadIdx.x, p = blockIdx.x;
    int lo = p << 9, span = min(N - lo, 512);
    int b8 = pbase8[p];
    for (int i = t; i < span; i += 256) {
        int r = rowptr[lo + i] + b8;
        srow[i] = r;
        cur[i] = r;
        sdi[i] = dinv[lo + i];
        rowptr[lo + i] = r;                 // write back fixed value for gather
    }
    if (t == 0) srow[span] = pbase8[p + 1];
    __syncthreads();
    int eBeg = pbase[p], eEnd = pbase[p + 1];
    for (int j = eBeg + t; j < eEnd; j += 256) {
        unsigned int v = binned[j];
        int s = (int)(v >> 9);
        int dl = (int)(v & 511u);
        int pos = atomicAdd(&cur[dl], 1);
        csrw[pos] = make_float2(__int_as_float(s << 7), dinv[s] * sdi[dl]);
    }
    __syncthreads();
    for (int i = t; i < span; i += 256) {
        int c = cur[i];                     // rowfixed + real deg
        float d = sdi[i];
        csrw[c] = make_float2(__int_as_float((lo + i) << 7), d * d);  // self loop
        int nxt = srow[i + 1];
        for (int k = c + 1; k < nxt; ++k)
            csrw[k] = make_float2(0.f, 0.f);                          // pads
    }
}

// MFMA GEMM: H[N,64](bf16) = X[N,FIN] @ W[FIN,64].  D = A*B with A=Wt (M=ofeat,
// K), B=X^T (K, N=node). One wave = 16 nodes x 64 ofeats. No LDS, no barriers.
// fp32 input cvt: +0x8000 half-up round + v_perm_b32 pack (3 VALU per 2 vals).
template <int FIN, bool F32IN>
__global__ __launch_bounds__(256) void gemm_mfma_kernel(const void* __restrict__ Xv,
                                                        const unsigned short* __restrict__ Wt,
                                                        unsigned short* __restrict__ H,
                                                        int N) {
    constexpr int KS = FIN / 32;
    int wave = threadIdx.x >> 6;
    int lane = threadIdx.x & 63;
    int r = lane & 15, g = lane >> 4;
    int node = blockIdx.x * 64 + wave * 16 + r;
    int nodeL = min(node, N - 1);

    bf16x8 afr[4][KS];
#pragma unroll
    for (int m = 0; m < 4; ++m)
#pragma unroll
        for (int s = 0; s < KS; ++s)
            afr[m][s] = *(const bf16x8*)&Wt[(m * 16 + r) * FIN + s * 32 + g * 8];

    f32x4 acc[4];
#pragma unroll
    for (int m = 0; m < 4; ++m) acc[m] = (f32x4){0.f, 0.f, 0.f, 0.f};

#pragma unroll
    for (int s = 0; s < KS; ++s) {
        bf16x8 bfr;
        if (F32IN) {
            const float* X = (const float*)Xv + (size_t)nodeL * FIN + s * 32 + g * 8;
            float4 lo = *(const float4*)X;
            float4 hi = *(const float4*)(X + 4);
            unsigned e0 = __float_as_uint(lo.x) + 0x8000u, e1 = __float_as_uint(lo.y) + 0x8000u;
            unsigned e2 = __float_as_uint(lo.z) + 0x8000u, e3 = __float_as_uint(lo.w) + 0x8000u;
            unsigned e4 = __float_as_uint(hi.x) + 0x8000u, e5 = __float_as_uint(hi.y) + 0x8000u;
            unsigned e6 = __float_as_uint(hi.z) + 0x8000u, e7 = __float_as_uint(hi.w) + 0x8000u;
            int4 rv;
            rv.x = __builtin_amdgcn_perm(e1, e0, 0x07060302);
            rv.y = __builtin_amdgcn_perm(e3, e2, 0x07060302);
            rv.z = __builtin_amdgcn_perm(e5, e4, 0x07060302);
            rv.w = __builtin_amdgcn_perm(e7, e6, 0x07060302);
            bfr = *(bf16x8*)&rv;
        } else {
            bfr = *(const bf16x8*)((const unsigned short*)Xv + (size_t)nodeL * FIN + s * 32 + g * 8);
        }
#pragma unroll
        for (int m = 0; m < 4; ++m)
            acc[m] = __builtin_amdgcn_mfma_f32_16x16x32_bf16(afr[m][s], bfr, acc[m], 0, 0, 0);
    }

    if (node < N) {
#pragma unroll
        for (int m = 0; m < 4; ++m) {
            ushort4 o;
            o.x = f2bf(acc[m][0]); o.y = f2bf(acc[m][1]);
            o.z = f2bf(acc[m][2]); o.w = f2bf(acc[m][3]);
            *(ushort4*)&H[(size_t)node * 64 + m * 16 + g * 4] = o;
        }
    }
}

// Gather step: NQ x 8 edges, unguarded (CSR 8-aligned, pads weight 0).
template <int NQ>
__device__ __forceinline__ void gstep(const float2* __restrict__ csrw,
                                      const char* __restrict__ hb,
                                      int e, int g, int fo, float acc[8]) {
    float2 c[NQ];
#pragma unroll
    for (int q = 0; q < NQ; ++q) c[q] = csrw[e + 8 * q + g];
    uint4 u[NQ];
#pragma unroll
    for (int q = 0; q < NQ; ++q)
        u[q] = *(const uint4*)(hb + __float_as_int(c[q].x) + fo);
#pragma unroll
    for (int q = 0; q < NQ; ++q) {
        float wq = c[q].y;
        acc[0] = fmaf(wq, bflo(u[q].x), acc[0]);
        acc[1] = fmaf(wq, bfhi(u[q].x), acc[1]);
        acc[2] = fmaf(wq, bflo(u[q].y), acc[2]);
        acc[3] = fmaf(wq, bfhi(u[q].y), acc[3]);
        acc[4] = fmaf(wq, bflo(u[q].z), acc[4]);
        acc[5] = fmaf(wq, bfhi(u[q].z), acc[5]);
        acc[6] = fmaf(wq, bflo(u[q].w), acc[6]);
        acc[7] = fmaf(wq, bfhi(u[q].w), acc[7]);
    }
}

// Gather v7: one wave per dst node. lane j: edge-slot g=j>>3, feat f=j&7.
// CSR 8-aligned incl. self loop; pads weight-0 -> NO predication anywhere.
// Tiered unguarded chunks 32/16/8; shfl_xor 8/16/32 reduce; bias+relu epilogue.
__global__ __launch_bounds__(256) void gather_kernel(const float2* __restrict__ csrw,
                                                     const int* __restrict__ rowptr,
                                                     const unsigned short* __restrict__ h,
                                                     const float* __restrict__ b,
                                                     unsigned short* __restrict__ aggb, int N) {
    int node = (blockIdx.x * 256 + threadIdx.x) >> 6;
    int lane = threadIdx.x & 63;
    if (node >= N) return;
    int g = lane >> 3;
    int f = lane & 7;
    int fo = f * 16;
    int beg = rowptr[node], end = rowptr[node + 1];

    float acc[8];
#pragma unroll
    for (int k = 0; k < 8; ++k) acc[k] = 0.f;

    const char* hb = (const char*)h;
    int e = beg;
    while (e + 32 <= end) { gstep<4>(csrw, hb, e, g, fo, acc); e += 32; }
    if (e + 16 <= end)    { gstep<2>(csrw, hb, e, g, fo, acc); e += 16; }
    if (e + 8 <= end)     { gstep<1>(csrw, hb, e, g, fo, acc); }

#pragma unroll
    for (int k = 0; k < 8; ++k) {
        float v = acc[k];
        v += __shfl_xor(v, 8);
        v += __shfl_xor(v, 16);
        v += __shfl_xor(v, 32);
        acc[k] = v;
    }
    if (g == 0) {
        float4 bv0 = *(const float4*)&b[f * 8];
        float4 bv1 = *(const float4*)&b[f * 8 + 4];
        float a0 = fmaxf(acc[0] + bv0.x, 0.f), a1 = fmaxf(acc[1] + bv0.y, 0.f);
        float a2 = fmaxf(acc[2] + bv0.z, 0.f), a3 = fmaxf(acc[3] + bv0.w, 0.f);
        float a4 = fmaxf(acc[4] + bv1.x, 0.f), a5 = fmaxf(acc[5] + bv1.y, 0.f);
        float a6 = fmaxf(acc[6] + bv1.z, 0.f), a7 = fmaxf(acc[7] + bv1.w, 0.f);
        uint4 o;
        o.x = ((unsigned)f2bf(a1) << 16) | f2bf(a0);
        o.y = ((unsigned)f2bf(a3) << 16) | f2bf(a2);
        o.z = ((unsigned)f2bf(a5) << 16) | f2bf(a4);
        o.w = ((unsigned)f2bf(a7) << 16) | f2bf(a6);
        *(uint4*)&aggb[((size_t)node << 6) + f * 8] = o;
    }
}

// batch is sorted: one WAVE per 64 contiguous nodes (lane = col), running
// accumulation, flush on graph change. agg is bf16, already relu'd.
__global__ __launch_bounds__(256) void pool_kernel(const unsigned short* __restrict__ hb,
                                                   const int* __restrict__ batch,
                                                   float* __restrict__ sums,
                                                   float* __restrict__ cnts, int N) {
    int col = threadIdx.x & 63;
    int wave = threadIdx.x >> 6;
    int base = blockIdx.x * 256 + wave * 64;
    float acc = 0.f, cnt = 0.f;
    int curg = -1;
    for (int j = 0; j < 64; ++j) {
        int node = base + j;
        if (node >= N) break;
        int g = batch[node];
        if (g != curg) {
            if (curg >= 0) {
                atomicAdd(&sums[curg * 64 + col], acc);
                if (col == 0) atomicAdd(&cnts[curg], cnt);
            }
            acc = 0.f; cnt = 0.f;
            curg = g;
        }
        acc += bf2f(hb[(size_t)node * 64 + col]);
        cnt += 1.f;
    }
    if (curg >= 0) {
        atomicAdd(&sums[curg * 64 + col], acc);
        if (col == 0) atomicAdd(&cnts[curg], cnt);
    }
}

// One thread per graph: pooled = sums/cnt, logits = pooled @ Wl + bl, softmax.
__global__ void final_kernel(const float* __restrict__ sums, const float* __restrict__ cnts,
                             const float* __restrict__ Wl, const float* __restrict__ bl,
                             float* __restrict__ out, int G) {
    int g = blockIdx.x * blockDim.x + threadIdx.x;
    if (g >= G) return;
    float inv = 1.0f / fmaxf(cnts[g], 1.0f);
    float logits[10];
#pragma unroll
    for (int k = 0; k < 10; ++k) logits[k] = bl[k];
    for (int c = 0; c < 64; ++c) {
        float p = sums[g * 64 + c] * inv;
#pragma unroll
        for (int k = 0; k < 10; ++k) logits[k] = fmaf(p, Wl[c * 10 + k], logits[k]);
    }
    float m = logits[0];
#pragma unroll
    for (int k = 1; k < 10; ++k) m = fmaxf(m, logits[k]);
    float se = 0.f;
#pragma unroll
    for (int k = 0; k < 10; ++k) { logits[k] = expf(logits[k] - m); se += logits[k]; }
    float is = 1.0f / se;
#pragma unroll
    for (int k = 0; k < 10; ++k) out[g * 10 + k] = logits[k] * is;
}

extern "C" void kernel_launch(void* const* d_in, const int* in_sizes, int n_in,
                              void* d_out, int out_size, void* d_ws, size_t ws_size,
                              hipStream_t stream) {
    const float* x    = (const float*)d_in[0];
    const int* edges  = (const int*)d_in[1];
    const int* batch  = (const int*)d_in[2];
    const float* W1   = (const float*)d_in[3];
    const float* b1   = (const float*)d_in[4];
    const float* W2   = (const float*)d_in[5];
    const float* b2   = (const float*)d_in[6];
    const float* W3   = (const float*)d_in[7];
    const float* b3   = (const float*)d_in[8];
    const float* Wl   = (const float*)d_in[9];
    const float* bl   = (const float*)d_in[10];

    const int N = in_sizes[0] / 128;   // 100000
    const int E = in_sizes[1] / 2;     // 1600000
    const int G = out_size / 10;       // 64
    const int* src = edges;
    const int* dst = edges + E;

    // workspace layout (floats). csrw sized for worst-case padding E + 8N.
    float* ws     = (float*)d_ws;
    unsigned short* h = (unsigned short*)ws;              // N*64 bf16 (slot: N*64 floats)
    unsigned short* aggb = (unsigned short*)(ws + (size_t)N * 64);  // N*64 bf16
    unsigned int* binned = (unsigned int*)ws;             // E uint, ALIASES h (dead before gemm1)
    size_t csrwOff = (size_t)2 * N * 64;
    float2* csrw  = (float2*)(ws + csrwOff);              // (E+8N) float2
    size_t o = csrwOff + (size_t)2 * (E + 8 * N);
    float* dinv   = ws + o;            o += N;            // N
    int*   rowptr = (int*)(ws + o);    o += N + 1;        // N+1
    int*   counts = (int*)(ws + o);    o += 256 * 256;
    int*   offs   = (int*)(ws + o);    o += 256 * 256;
    int*   pbase  = (int*)(ws + o);    o += 257;
    float* sums   = ws + o;            o += (size_t)G * 64;
    float* cnts   = ws + o;            o += G;
    int*   partTot8 = (int*)(ws + o);  o += 256;
    int*   pbase8 = (int*)(ws + o);    o += 257;
    unsigned short* Wt1 = (unsigned short*)(ws + o);      // 64*128 + 2*64*64 shorts
    unsigned short* Wt2 = Wt1 + 64 * 128;
    unsigned short* Wt3 = Wt2 + 64 * 64;

    const int gemmGrid = (N + 63) / 64;
    const int gatherGrid = (N + 3) / 4;
    const int P = (N + 511) >> 9;                 // 196 partitions of 512 nodes
    const int C = (E + 255) / 256;                // edges per chunk (256 chunks)

    // sort -> padded CSR {src_byte_off, w} with self-loops + weight-0 pads
    hist_kernel<<<260, 256, 0, stream>>>(dst, counts, E, P, C,
                                         W1, W2, W3, Wt1, Wt2, Wt3, sums, G);
    pscan_kernel<<<1, 256, 0, stream>>>(counts, pbase, P);
    offs_kernel<<<P, 256, 0, stream>>>(counts, pbase, offs);
    bin_kernel<<<256, 256, 0, stream>>>(src, dst, offs, binned, E, P, C);
    lsortA_kernel<<<P, 512, 0, stream>>>(binned, pbase, rowptr, dinv, partTot8, N);
    pscan8_kernel<<<1, 256, 0, stream>>>(partTot8, pbase8, rowptr, P, N);
    lsortB_kernel<<<P, 256, 0, stream>>>(binned, pbase, pbase8, rowptr, dinv, csrw, N);

    // layer 1: x[N,128] @ W1 -> h bf16 (overwrites binned; build complete); gather
    gemm_mfma_kernel<128, true><<<gemmGrid, 256, 0, stream>>>(x, Wt1, h, N);
    gather_kernel<<<gatherGrid, 256, 0, stream>>>(csrw, rowptr, h, b1, aggb, N);

    // layer 2
    gemm_mfma_kernel<64, false><<<gemmGrid, 256, 0, stream>>>(aggb, Wt2, h, N);
    gather_kernel<<<gatherGrid, 256, 0, stream>>>(csrw, rowptr, h, b2, aggb, N);

    // layer 3
    gemm_mfma_kernel<64, false><<<gemmGrid, 256, 0, stream>>>(aggb, Wt3, h, N);
    gather_kernel<<<gatherGrid, 256, 0, stream>>>(csrw, rowptr, h, b3, aggb, N);

    // mean-pool per graph + head + softmax (sums/cnts zeroed in hist's extra block)
    pool_kernel<<<(N + 255) / 256, 256, 0, stream>>>(aggb, batch, sums, cnts, N);
    final_kernel<<<1, 64, 0, stream>>>(sums, cnts, Wl, bl, (float*)d_out, G);
}

// Round 4
// 367.503 us; speedup vs baseline: 1.2453x; 1.0538x over previous
//
#include <hip/hip_runtime.h>
#include <math.h>

// GCN via CSR gather. CSR(dst) built with a two-level binned counting sort where
// node degrees are derived INSIDE the partition sort (lsortA LDS histogram).
// 3x (MFMA GEMM -> gather-agg[+relu,bf16]) -> mean-pool -> head -> softmax.
//
// Pool v2 (this round): v1 was a rolled 64-iter loop, one dependent scalar
// batch load + 128B row load per iter -> pure latency (VALUBusy 2.6%, HBM 2%,
// 44us for 12.8MB). Now: wave per 32 nodes, batch preloaded once (coalesced) +
// __shfl per node, all 32 row loads issued upfront (one vmcnt wall). ~4us.
// lsortB folds pscan8 (in-block scan of partition totals) -> one fewer dispatch.
// GEMM v3 (this round): B-fragment loads were 16B/lane scattered over 16 rows
// (4x L2 over-fetch on X). X tile now staged through LDS with coalesced loads
// (fp32->bf16 in staging), fragments via ds_read_b128 (+8-half row pad).
//
// Gather v7 (round 3): CSR padded to 8-edge alignment, self-loop folded in as a
// real edge {node<<7, dinv^2}, pads {0,0.0} -> fully unguarded tiered chunks
// (32/16/8), no predication. Gather v6 (round 1): lane j=(edge g=j>>3, feat16B
// f=j&7), dwordx4 row loads -> 8 edges per VMEM instr. 64.4 -> 47.5 -> 45.2 -> ~40us.
// N=100000 nodes, E=1.6M edges, nhid=64, Poisson(16) degrees.

typedef __attribute__((ext_vector_type(8))) short bf16x8;
typedef __attribute__((ext_vector_type(4))) float f32x4;

__device__ __forceinline__ unsigned short f2bf(float f) {
    unsigned int u = __float_as_uint(f);
    u += 0x7fffu + ((u >> 16) & 1u);   // round-to-nearest-even
    return (unsigned short)(u >> 16);
}
__device__ __forceinline__ float bf2f(unsigned short u) {
    return __uint_as_float((unsigned int)u << 16);
}
__device__ __forceinline__ float bflo(unsigned int u) {
    return __uint_as_float(u << 16);
}
__device__ __forceinline__ float bfhi(unsigned int u) {
    return __uint_as_float(u & 0xffff0000u);
}

// ---- binned counting sort: partition = dst>>9 (512 nodes), P<=256, 256 chunks ----
// hist fused: blocks 256..258 = W->Wt bf16 transpose; block 259 = zero sums/cnts.

__global__ __launch_bounds__(256) void hist_kernel(const int* __restrict__ dst,
                                                   int* __restrict__ counts,
                                                   int E, int P, int C,
                                                   const float* __restrict__ W1,
                                                   const float* __restrict__ W2,
                                                   const float* __restrict__ W3,
                                                   unsigned short* __restrict__ Wt1,
                                                   unsigned short* __restrict__ Wt2,
                                                   unsigned short* __restrict__ Wt3,
                                                   float* __restrict__ sums, int G) {
    int t = threadIdx.x, b = blockIdx.x;
    if (b >= 256) {
        int xb = b - 256;
        if (xb < 3) {           // prepw
            const float* W = (xb == 0) ? W1 : ((xb == 1) ? W2 : W3);
            unsigned short* Wt = (xb == 0) ? Wt1 : ((xb == 1) ? Wt2 : Wt3);
            int K = (xb == 0) ? 128 : 64;
            int o = t & 63;
            for (int k = t >> 6; k < K; k += 4)
                Wt[o * K + k] = f2bf(W[k * 64 + o]);
        } else {                // zero sums+cnts (G*65 floats)
            for (int i = t; i < G * 65; i += 256) sums[i] = 0.f;
        }
        return;
    }
    __shared__ int hist[256];
    if (t < P) hist[t] = 0;
    __syncthreads();
    int beg = b * C, end = min(E, beg + C);
    for (int e = beg + t; e < end; e += 256)
        atomicAdd(&hist[dst[e] >> 9], 1);
    __syncthreads();
    if (t < P) counts[t * 256 + b] = hist[t];
}

__global__ __launch_bounds__(256) void pscan_kernel(const int* __restrict__ counts,
                                                    int* __restrict__ pbase,
                                                    int P) {
    __shared__ int s[256];
    int t = threadIdx.x;
    int v = 0;
    if (t < P)
        for (int b = 0; b < 256; ++b) v += counts[t * 256 + b];
    s[t] = v;
    __syncthreads();
    for (int off = 1; off < 256; off <<= 1) {
        int u = (t >= off) ? s[t - off] : 0;
        __syncthreads();
        s[t] += u;
        __syncthreads();
    }
    if (t < P) pbase[t] = s[t] - v;
    if (t == 255) pbase[P] = s[255];
}

__global__ __launch_bounds__(256) void offs_kernel(const int* __restrict__ counts,
                                                   const int* __restrict__ pbase,
                                                   int* __restrict__ offs) {
    __shared__ int s[256];
    int t = threadIdx.x, p = blockIdx.x;
    int v = counts[p * 256 + t];
    s[t] = v;
    __syncthreads();
    for (int off = 1; off < 256; off <<= 1) {
        int u = (t >= off) ? s[t - off] : 0;
        __syncthreads();
        s[t] += u;
        __syncthreads();
    }
    offs[p * 256 + t] = pbase[p] + s[t] - v;
}

__global__ __launch_bounds__(256) void bin_kernel(const int* __restrict__ src,
                                                  const int* __restrict__ dst,
                                                  const int* __restrict__ offs,
                                                  unsigned int* __restrict__ binned,
                                                  int E, int P, int C) {
    __shared__ int cur[256];
    int t = threadIdx.x, b = blockIdx.x;
    if (t < P) cur[t] = offs[t * 256 + b];
    __syncthreads();
    int beg = b * C, end = min(E, beg + C);
    for (int e = beg + t; e < end; e += 256) {
        int d = dst[e], s = src[e];
        int pos = atomicAdd(&cur[d >> 9], 1);
        binned[pos] = ((unsigned int)s << 9) | (unsigned int)(d & 511);
    }
}

// Per-node real degree (LDS histogram) -> 8-aligned span align8(deg+1) (+1 = self
// loop). rowptr gets LOCAL aligned offsets; partTot8[p] = partition aligned total.
__global__ __launch_bounds__(512) void lsortA_kernel(const unsigned int* __restrict__ binned,
                                                     const int* __restrict__ pbase,
                                                     int* __restrict__ rowptr,
                                                     float* __restrict__ dinv,
                                                     int* __restrict__ partTot8, int N) {
    __shared__ int ldeg[512];
    __shared__ int s[512];
    int t = threadIdx.x, p = blockIdx.x;
    int lo = p << 9;
    ldeg[t] = 0;
    __syncthreads();
    int eBeg = pbase[p], eEnd = pbase[p + 1];
    for (int j = eBeg + t; j < eEnd; j += 512)
        atomicAdd(&ldeg[binned[j] & 511u], 1);
    __syncthreads();
    int real = ldeg[t];
    int a = (lo + t < N) ? ((real + 1 + 7) & ~7) : 0;   // +1 self, pad to 8
    s[t] = a;
    __syncthreads();
    for (int off = 1; off < 512; off <<= 1) {
        int u = (t >= off) ? s[t - off] : 0;
        __syncthreads();
        s[t] += u;
        __syncthreads();
    }
    if (lo + t < N) {
        rowptr[lo + t] = s[t] - a;                       // local aligned offset
        dinv[lo + t] = rsqrtf((float)(real + 1));
    }
    if (t == 511) partTot8[p] = s[511];
}

// In-block scan of partTot8 -> pbase8 (pscan8 folded in); fix rowptr to global
// aligned offsets, scatter real edges, append self edge, fill pads {0,0}.
__global__ __launch_bounds__(256) void lsortB_kernel(const unsigned int* __restrict__ binned,
                                                     const int* __restrict__ pbase,
                                                     const int* __restrict__ partTot8,
                                                     int* __restrict__ rowptr,
                                                     const float* __restrict__ dinv,
                                                     float2* __restrict__ csrw, int N, int P) {
    __shared__ int s[256];
    __shared__ int srow[513];
    __shared__ int cur[512];
    __shared__ float sdi[512];
    int t = threadIdx.x, p = blockIdx.x;
    // exclusive scan of partition aligned totals (P <= 256)
    int v = (t < P) ? partTot8[t] : 0;
    s[t] = v;
    __syncthreads();
    for (int off = 1; off < 256; off <<= 1) {
        int u = (t >= off) ? s[t - off] : 0;
        __syncthreads();
        s[t] += u;
        __syncthreads();
    }
    int b8 = s[p] - partTot8[p];        // exclusive at p
    int endP = s[p];                    // exclusive at p+1
    if (p == 0 && t == 0) rowptr[N] = s[P - 1];   // grand total
    int lo = p << 9, span = min(N - lo, 512);
    for (int i = t; i < span; i += 256) {
        int r = rowptr[lo + i] + b8;
        srow[i] = r;
        cur[i] = r;
        sdi[i] = dinv[lo + i];
        rowptr[lo + i] = r;             // write back fixed value for gather
    }
    if (t == 0) srow[span] = endP;
    __syncthreads();
    int eBeg = pbase[p], eEnd = pbase[p + 1];
    for (int j = eBeg + t; j < eEnd; j += 256) {
        unsigned int vv = binned[j];
        int sr = (int)(vv >> 9);
        int dl = (int)(vv & 511u);
        int pos = atomicAdd(&cur[dl], 1);
        csrw[pos] = make_float2(__int_as_float(sr << 7), dinv[sr] * sdi[dl]);
    }
    __syncthreads();
    for (int i = t; i < span; i += 256) {
        int c = cur[i];                 // rowfixed + real deg
        float d = sdi[i];
        csrw[c] = make_float2(__int_as_float((lo + i) << 7), d * d);  // self loop
        int nxt = srow[i + 1];
        for (int k = c + 1; k < nxt; ++k)
            csrw[k] = make_float2(0.f, 0.f);                          // pads
    }
}

// MFMA GEMM v3: H[N,64](bf16) = X[N,FIN] @ W[FIN,64].  D = A*B with A=Wt
// (M=ofeat, K), B=X^T (K, N=node). One wave = 16 nodes x 64 ofeats.
// X tile staged through LDS (coalesced global loads, fp32->bf16 in staging);
// B-fragments via ds_read_b128 from padded rows (LDP = FIN+8 halves).
template <int FIN, bool F32IN>
__global__ __launch_bounds__(256) void gemm_mfma_kernel(const void* __restrict__ Xv,
                                                        const unsigned short* __restrict__ Wt,
                                                        unsigned short* __restrict__ H,
                                                        int N) {
    constexpr int KS = FIN / 32;
    constexpr int LDP = FIN + 8;
    __shared__ unsigned short sX[64 * LDP];
    int tid = threadIdx.x;
    int rowBase = blockIdx.x * 64;

    if (F32IN) {
        for (int i = tid * 4; i < 64 * FIN; i += 1024) {
            int r = i / FIN, c = i - r * FIN;
            int gr = min(rowBase + r, N - 1);
            float4 vv = *(const float4*)((const float*)Xv + (size_t)gr * FIN + c);
            unsigned e0 = __float_as_uint(vv.x) + 0x8000u, e1 = __float_as_uint(vv.y) + 0x8000u;
            unsigned e2 = __float_as_uint(vv.z) + 0x8000u, e3 = __float_as_uint(vv.w) + 0x8000u;
            uint2 pk;
            pk.x = __builtin_amdgcn_perm(e1, e0, 0x07060302);
            pk.y = __builtin_amdgcn_perm(e3, e2, 0x07060302);
            *(uint2*)&sX[r * LDP + c] = pk;
        }
    } else {
        for (int i = tid * 8; i < 64 * FIN; i += 2048) {
            int r = i / FIN, c = i - r * FIN;
            int gr = min(rowBase + r, N - 1);
            uint4 vv = *(const uint4*)((const unsigned short*)Xv + (size_t)gr * FIN + c);
            *(uint4*)&sX[r * LDP + c] = vv;
        }
    }
    __syncthreads();

    int wave = tid >> 6;
    int lane = tid & 63;
    int r = lane & 15, g = lane >> 4;
    int node = rowBase + wave * 16 + r;

    bf16x8 afr[4][KS];
#pragma unroll
    for (int m = 0; m < 4; ++m)
#pragma unroll
        for (int s = 0; s < KS; ++s)
            afr[m][s] = *(const bf16x8*)&Wt[(m * 16 + r) * FIN + s * 32 + g * 8];

    f32x4 acc[4];
#pragma unroll
    for (int m = 0; m < 4; ++m) acc[m] = (f32x4){0.f, 0.f, 0.f, 0.f};

#pragma unroll
    for (int s = 0; s < KS; ++s) {
        bf16x8 bfr = *(const bf16x8*)&sX[(wave * 16 + r) * LDP + s * 32 + g * 8];
#pragma unroll
        for (int m = 0; m < 4; ++m)
            acc[m] = __builtin_amdgcn_mfma_f32_16x16x32_bf16(afr[m][s], bfr, acc[m], 0, 0, 0);
    }

    if (node < N) {
#pragma unroll
        for (int m = 0; m < 4; ++m) {
            ushort4 o;
            o.x = f2bf(acc[m][0]); o.y = f2bf(acc[m][1]);
            o.z = f2bf(acc[m][2]); o.w = f2bf(acc[m][3]);
            *(ushort4*)&H[(size_t)node * 64 + m * 16 + g * 4] = o;
        }
    }
}

// Gather step: NQ x 8 edges, unguarded (CSR 8-aligned, pads weight 0).
template <int NQ>
__device__ __forceinline__ void gstep(const float2* __restrict__ csrw,
                                      const char* __restrict__ hb,
                                      int e, int g, int fo, float acc[8]) {
    float2 c[NQ];
#pragma unroll
    for (int q = 0; q < NQ; ++q) c[q] = csrw[e + 8 * q + g];
    uint4 u[NQ];
#pragma unroll
    for (int q = 0; q < NQ; ++q)
        u[q] = *(const uint4*)(hb + __float_as_int(c[q].x) + fo);
#pragma unroll
    for (int q = 0; q < NQ; ++q) {
        float wq = c[q].y;
        acc[0] = fmaf(wq, bflo(u[q].x), acc[0]);
        acc[1] = fmaf(wq, bfhi(u[q].x), acc[1]);
        acc[2] = fmaf(wq, bflo(u[q].y), acc[2]);
        acc[3] = fmaf(wq, bfhi(u[q].y), acc[3]);
        acc[4] = fmaf(wq, bflo(u[q].z), acc[4]);
        acc[5] = fmaf(wq, bfhi(u[q].z), acc[5]);
        acc[6] = fmaf(wq, bflo(u[q].w), acc[6]);
        acc[7] = fmaf(wq, bfhi(u[q].w), acc[7]);
    }
}

// Gather v7: one wave per dst node. lane j: edge-slot g=j>>3, feat f=j&7.
// CSR 8-aligned incl. self loop; pads weight-0 -> NO predication anywhere.
// Tiered unguarded chunks 32/16/8; shfl_xor 8/16/32 reduce; bias+relu epilogue.
__global__ __launch_bounds__(256) void gather_kernel(const float2* __restrict__ csrw,
                                                     const int* __restrict__ rowptr,
                                                     const unsigned short* __restrict__ h,
                                                     const float* __restrict__ b,
                                                     unsigned short* __restrict__ aggb, int N) {
    int node = (blockIdx.x * 256 + threadIdx.x) >> 6;
    int lane = threadIdx.x & 63;
    if (node >= N) return;
    int g = lane >> 3;
    int f = lane & 7;
    int fo = f * 16;
    int beg = rowptr[node], end = rowptr[node + 1];

    float acc[8];
#pragma unroll
    for (int k = 0; k < 8; ++k) acc[k] = 0.f;

    const char* hb = (const char*)h;
    int e = beg;
    while (e + 32 <= end) { gstep<4>(csrw, hb, e, g, fo, acc); e += 32; }
    if (e + 16 <= end)    { gstep<2>(csrw, hb, e, g, fo, acc); e += 16; }
    if (e + 8 <= end)     { gstep<1>(csrw, hb, e, g, fo, acc); }

#pragma unroll
    for (int k = 0; k < 8; ++k) {
        float v = acc[k];
        v += __shfl_xor(v, 8);
        v += __shfl_xor(v, 16);
        v += __shfl_xor(v, 32);
        acc[k] = v;
    }
    if (g == 0) {
        float4 bv0 = *(const float4*)&b[f * 8];
        float4 bv1 = *(const float4*)&b[f * 8 + 4];
        float a0 = fmaxf(acc[0] + bv0.x, 0.f), a1 = fmaxf(acc[1] + bv0.y, 0.f);
        float a2 = fmaxf(acc[2] + bv0.z, 0.f), a3 = fmaxf(acc[3] + bv0.w, 0.f);
        float a4 = fmaxf(acc[4] + bv1.x, 0.f), a5 = fmaxf(acc[5] + bv1.y, 0.f);
        float a6 = fmaxf(acc[6] + bv1.z, 0.f), a7 = fmaxf(acc[7] + bv1.w, 0.f);
        uint4 o;
        o.x = ((unsigned)f2bf(a1) << 16) | f2bf(a0);
        o.y = ((unsigned)f2bf(a3) << 16) | f2bf(a2);
        o.z = ((unsigned)f2bf(a5) << 16) | f2bf(a4);
        o.w = ((unsigned)f2bf(a7) << 16) | f2bf(a6);
        *(uint4*)&aggb[((size_t)node << 6) + f * 8] = o;
    }
}

// Pool v2: one wave per 32 contiguous nodes (lane = col). batch preloaded once
// (coalesced) + __shfl per node; all 32 row loads (128B each, 4KB contiguous
// per wave) issued upfront; wave-uniform flush on graph change.
__global__ __launch_bounds__(256) void pool_kernel(const unsigned short* __restrict__ hb,
                                                   const int* __restrict__ batch,
                                                   float* __restrict__ sums,
                                                   float* __restrict__ cnts, int N) {
    int lane = threadIdx.x & 63;
    int wid = (blockIdx.x * 256 + threadIdx.x) >> 6;
    int base = wid * 32;
    if (base >= N) return;
    int nn = min(N - base, 32);
    int bl = batch[base + min(lane & 31, nn - 1)];

    float v[32];
#pragma unroll
    for (int j = 0; j < 32; ++j) {
        int node = base + min(j, nn - 1);
        v[j] = bf2f(hb[(size_t)node * 64 + lane]);
    }

    int curg = __shfl(bl, 0);
    float acc = 0.f, cnt = 0.f;
#pragma unroll
    for (int j = 0; j < 32; ++j) {
        if (j < nn) {
            int g = __shfl(bl, j);
            if (g != curg) {
                atomicAdd(&sums[curg * 64 + lane], acc);
                if (lane == 0) atomicAdd(&cnts[curg], cnt);
                acc = 0.f; cnt = 0.f; curg = g;
            }
            acc += v[j]; cnt += 1.f;
        }
    }
    atomicAdd(&sums[curg * 64 + lane], acc);
    if (lane == 0) atomicAdd(&cnts[curg], cnt);
}

// One thread per graph: pooled = sums/cnt, logits = pooled @ Wl + bl, softmax.
__global__ void final_kernel(const float* __restrict__ sums, const float* __restrict__ cnts,
                             const float* __restrict__ Wl, const float* __restrict__ bl,
                             float* __restrict__ out, int G) {
    int g = blockIdx.x * blockDim.x + threadIdx.x;
    if (g >= G) return;
    float inv = 1.0f / fmaxf(cnts[g], 1.0f);
    float logits[10];
#pragma unroll
    for (int k = 0; k < 10; ++k) logits[k] = bl[k];
    for (int c = 0; c < 64; ++c) {
        float p = sums[g * 64 + c] * inv;
#pragma unroll
        for (int k = 0; k < 10; ++k) logits[k] = fmaf(p, Wl[c * 10 + k], logits[k]);
    }
    float m = logits[0];
#pragma unroll
    for (int k = 1; k < 10; ++k) m = fmaxf(m, logits[k]);
    float se = 0.f;
#pragma unroll
    for (int k = 0; k < 10; ++k) { logits[k] = expf(logits[k] - m); se += logits[k]; }
    float is = 1.0f / se;
#pragma unroll
    for (int k = 0; k < 10; ++k) out[g * 10 + k] = logits[k] * is;
}

extern "C" void kernel_launch(void* const* d_in, const int* in_sizes, int n_in,
                              void* d_out, int out_size, void* d_ws, size_t ws_size,
                              hipStream_t stream) {
    const float* x    = (const float*)d_in[0];
    const int* edges  = (const int*)d_in[1];
    const int* batch  = (const int*)d_in[2];
    const float* W1   = (const float*)d_in[3];
    const float* b1   = (const float*)d_in[4];
    const float* W2   = (const float*)d_in[5];
    const float* b2   = (const float*)d_in[6];
    const float* W3   = (const float*)d_in[7];
    const float* b3   = (const float*)d_in[8];
    const float* Wl   = (const float*)d_in[9];
    const float* bl   = (const float*)d_in[10];

    const int N = in_sizes[0] / 128;   // 100000
    const int E = in_sizes[1] / 2;     // 1600000
    const int G = out_size / 10;       // 64
    const int* src = edges;
    const int* dst = edges + E;

    // workspace layout (floats). csrw sized for worst-case padding E + 8N.
    float* ws     = (float*)d_ws;
    unsigned short* h = (unsigned short*)ws;              // N*64 bf16 (slot: N*64 floats)
    unsigned short* aggb = (unsigned short*)(ws + (size_t)N * 64);  // N*64 bf16
    unsigned int* binned = (unsigned int*)ws;             // E uint, ALIASES h (dead before gemm1)
    size_t csrwOff = (size_t)2 * N * 64;
    float2* csrw  = (float2*)(ws + csrwOff);              // (E+8N) float2
    size_t o = csrwOff + (size_t)2 * (E + 8 * N);
    float* dinv   = ws + o;            o += N;            // N
    int*   rowptr = (int*)(ws + o);    o += N + 1;        // N+1
    int*   counts = (int*)(ws + o);    o += 256 * 256;
    int*   offs   = (int*)(ws + o);    o += 256 * 256;
    int*   pbase  = (int*)(ws + o);    o += 257;
    float* sums   = ws + o;            o += (size_t)G * 64;
    float* cnts   = ws + o;            o += G;
    int*   partTot8 = (int*)(ws + o);  o += 256;
    unsigned short* Wt1 = (unsigned short*)(ws + o);      // 64*128 + 2*64*64 shorts
    unsigned short* Wt2 = Wt1 + 64 * 128;
    unsigned short* Wt3 = Wt2 + 64 * 64;

    const int gemmGrid = (N + 63) / 64;
    const int gatherGrid = (N + 3) / 4;
    const int poolGrid = ((N + 31) / 32 + 3) / 4;
    const int P = (N + 511) >> 9;                 // 196 partitions of 512 nodes
    const int C = (E + 255) / 256;                // edges per chunk (256 chunks)

    // sort -> padded CSR {src_byte_off, w} with self-loops + weight-0 pads
    hist_kernel<<<260, 256, 0, stream>>>(dst, counts, E, P, C,
                                         W1, W2, W3, Wt1, Wt2, Wt3, sums, G);
    pscan_kernel<<<1, 256, 0, stream>>>(counts, pbase, P);
    offs_kernel<<<P, 256, 0, stream>>>(counts, pbase, offs);
    bin_kernel<<<256, 256, 0, stream>>>(src, dst, offs, binned, E, P, C);
    lsortA_kernel<<<P, 512, 0, stream>>>(binned, pbase, rowptr, dinv, partTot8, N);
    lsortB_kernel<<<P, 256, 0, stream>>>(binned, pbase, partTot8, rowptr, dinv, csrw, N, P);

    // layer 1: x[N,128] @ W1 -> h bf16 (overwrites binned; build complete); gather
    gemm_mfma_kernel<128, true><<<gemmGrid, 256, 0, stream>>>(x, Wt1, h, N);
    gather_kernel<<<gatherGrid, 256, 0, stream>>>(csrw, rowptr, h, b1, aggb, N);

    // layer 2
    gemm_mfma_kernel<64, false><<<gemmGrid, 256, 0, stream>>>(aggb, Wt2, h, N);
    gather_kernel<<<gatherGrid, 256, 0, stream>>>(csrw, rowptr, h, b2, aggb, N);

    // layer 3
    gemm_mfma_kernel<64, false><<<gemmGrid, 256, 0, stream>>>(aggb, Wt3, h, N);
    gather_kernel<<<gatherGrid, 256, 0, stream>>>(csrw, rowptr, h, b3, aggb, N);

    // mean-pool per graph + head + softmax (sums/cnts zeroed in hist's extra block)
    pool_kernel<<<poolGrid, 256, 0, stream>>>(aggb, batch, sums, cnts, N);
    final_kernel<<<1, 64, 0, stream>>>(sums, cnts, Wl, bl, (float*)d_out, G);
}

// Round 5
// 358.734 us; speedup vs baseline: 1.2757x; 1.0244x over previous
//
#include <hip/hip_runtime.h>
#include <math.h>

// GCN via CSR gather. CSR(dst) built with a two-level binned counting sort where
// node degrees are derived INSIDE the partition sort (lsortA LDS histogram).
// 3x (MFMA GEMM -> gather-agg[+relu,bf16]) -> mean-pool -> head -> softmax.
//
// Gather v8 (this round): v7 serialized the remainder tiers (16 then 8) -> the
// dominant span-24 nodes (53%, Poisson(16) degrees) paid TWO dependent memory
// round-trips. Now: nb = span>>3 dispatched as ONE unguarded gstep<nb> (1..4),
// while-loop only for the rare span>32. Accumulators packed f32x2 via
// __builtin_elementwise_fma -> v_pk_fma_f32 (8 fma -> 4 pk_fma per 16B).
//
// Pool v2 (round 4): wave per 32 nodes, batch preloaded + __shfl, all 32 row
// loads upfront -> off top-5 (was 44us latency-bound).
// GEMM v3 (round 4): X staged via LDS coalesced (fp32->bf16 in staging),
// fragments via ds_read_b128, MFMA 16x16x32, A=Wt, B=X^T. No launch-bound cap.
// Gather v7 (round 3): CSR padded to 8-edge alignment, self-loop folded in as
// real edge {node<<7, dinv^2}, pads {0,0.0} -> fully unguarded chunks.
// Gather v6 (round 1): lane j=(edge g=j>>3, feat16B f=j&7), dwordx4 row loads.
// 64.4 -> 47.5 -> 45.2 -> ~40 -> 42.9(v7 measured) us.
// N=100000 nodes, E=1.6M edges, nhid=64, Poisson(16) degrees.

typedef __attribute__((ext_vector_type(8))) short bf16x8;
typedef __attribute__((ext_vector_type(4))) float f32x4;
typedef __attribute__((ext_vector_type(2))) float f32x2;

__device__ __forceinline__ unsigned short f2bf(float f) {
    unsigned int u = __float_as_uint(f);
    u += 0x7fffu + ((u >> 16) & 1u);   // round-to-nearest-even
    return (unsigned short)(u >> 16);
}
__device__ __forceinline__ float bf2f(unsigned short u) {
    return __uint_as_float((unsigned int)u << 16);
}
__device__ __forceinline__ float bflo(unsigned int u) {
    return __uint_as_float(u << 16);
}
__device__ __forceinline__ float bfhi(unsigned int u) {
    return __uint_as_float(u & 0xffff0000u);
}

// ---- binned counting sort: partition = dst>>9 (512 nodes), P<=256, 256 chunks ----
// hist fused: blocks 256..258 = W->Wt bf16 transpose; block 259 = zero sums/cnts.

__global__ __launch_bounds__(256) void hist_kernel(const int* __restrict__ dst,
                                                   int* __restrict__ counts,
                                                   int E, int P, int C,
                                                   const float* __restrict__ W1,
                                                   const float* __restrict__ W2,
                                                   const float* __restrict__ W3,
                                                   unsigned short* __restrict__ Wt1,
                                                   unsigned short* __restrict__ Wt2,
                                                   unsigned short* __restrict__ Wt3,
                                                   float* __restrict__ sums, int G) {
    int t = threadIdx.x, b = blockIdx.x;
    if (b >= 256) {
        int xb = b - 256;
        if (xb < 3) {           // prepw
            const float* W = (xb == 0) ? W1 : ((xb == 1) ? W2 : W3);
            unsigned short* Wt = (xb == 0) ? Wt1 : ((xb == 1) ? Wt2 : Wt3);
            int K = (xb == 0) ? 128 : 64;
            int o = t & 63;
            for (int k = t >> 6; k < K; k += 4)
                Wt[o * K + k] = f2bf(W[k * 64 + o]);
        } else {                // zero sums+cnts (G*65 floats)
            for (int i = t; i < G * 65; i += 256) sums[i] = 0.f;
        }
        return;
    }
    __shared__ int hist[256];
    if (t < P) hist[t] = 0;
    __syncthreads();
    int beg = b * C, end = min(E, beg + C);
    for (int e = beg + t; e < end; e += 256)
        atomicAdd(&hist[dst[e] >> 9], 1);
    __syncthreads();
    if (t < P) counts[t * 256 + b] = hist[t];
}

__global__ __launch_bounds__(256) void pscan_kernel(const int* __restrict__ counts,
                                                    int* __restrict__ pbase,
                                                    int P) {
    __shared__ int s[256];
    int t = threadIdx.x;
    int v = 0;
    if (t < P)
        for (int b = 0; b < 256; ++b) v += counts[t * 256 + b];
    s[t] = v;
    __syncthreads();
    for (int off = 1; off < 256; off <<= 1) {
        int u = (t >= off) ? s[t - off] : 0;
        __syncthreads();
        s[t] += u;
        __syncthreads();
    }
    if (t < P) pbase[t] = s[t] - v;
    if (t == 255) pbase[P] = s[255];
}

__global__ __launch_bounds__(256) void offs_kernel(const int* __restrict__ counts,
                                                   const int* __restrict__ pbase,
                                                   int* __restrict__ offs) {
    __shared__ int s[256];
    int t = threadIdx.x, p = blockIdx.x;
    int v = counts[p * 256 + t];
    s[t] = v;
    __syncthreads();
    for (int off = 1; off < 256; off <<= 1) {
        int u = (t >= off) ? s[t - off] : 0;
        __syncthreads();
        s[t] += u;
        __syncthreads();
    }
    offs[p * 256 + t] = pbase[p] + s[t] - v;
}

__global__ __launch_bounds__(256) void bin_kernel(const int* __restrict__ src,
                                                  const int* __restrict__ dst,
                                                  const int* __restrict__ offs,
                                                  unsigned int* __restrict__ binned,
                                                  int E, int P, int C) {
    __shared__ int cur[256];
    int t = threadIdx.x, b = blockIdx.x;
    if (t < P) cur[t] = offs[t * 256 + b];
    __syncthreads();
    int beg = b * C, end = min(E, beg + C);
    for (int e = beg + t; e < end; e += 256) {
        int d = dst[e], s = src[e];
        int pos = atomicAdd(&cur[d >> 9], 1);
        binned[pos] = ((unsigned int)s << 9) | (unsigned int)(d & 511);
    }
}

// Per-node real degree (LDS histogram) -> 8-aligned span align8(deg+1) (+1 = self
// loop). rowptr gets LOCAL aligned offsets; partTot8[p] = partition aligned total.
__global__ __launch_bounds__(512) void lsortA_kernel(const unsigned int* __restrict__ binned,
                                                     const int* __restrict__ pbase,
                                                     int* __restrict__ rowptr,
                                                     float* __restrict__ dinv,
                                                     int* __restrict__ partTot8, int N) {
    __shared__ int ldeg[512];
    __shared__ int s[512];
    int t = threadIdx.x, p = blockIdx.x;
    int lo = p << 9;
    ldeg[t] = 0;
    __syncthreads();
    int eBeg = pbase[p], eEnd = pbase[p + 1];
    for (int j = eBeg + t; j < eEnd; j += 512)
        atomicAdd(&ldeg[binned[j] & 511u], 1);
    __syncthreads();
    int real = ldeg[t];
    int a = (lo + t < N) ? ((real + 1 + 7) & ~7) : 0;   // +1 self, pad to 8
    s[t] = a;
    __syncthreads();
    for (int off = 1; off < 512; off <<= 1) {
        int u = (t >= off) ? s[t - off] : 0;
        __syncthreads();
        s[t] += u;
        __syncthreads();
    }
    if (lo + t < N) {
        rowptr[lo + t] = s[t] - a;                       // local aligned offset
        dinv[lo + t] = rsqrtf((float)(real + 1));
    }
    if (t == 511) partTot8[p] = s[511];
}

// In-block scan of partTot8 -> pbase8 (pscan8 folded in); fix rowptr to global
// aligned offsets, scatter real edges, append self edge, fill pads {0,0}.
__global__ __launch_bounds__(256) void lsortB_kernel(const unsigned int* __restrict__ binned,
                                                     const int* __restrict__ pbase,
                                                     const int* __restrict__ partTot8,
                                                     int* __restrict__ rowptr,
                                                     const float* __restrict__ dinv,
                                                     float2* __restrict__ csrw, int N, int P) {
    __shared__ int s[256];
    __shared__ int srow[513];
    __shared__ int cur[512];
    __shared__ float sdi[512];
    int t = threadIdx.x, p = blockIdx.x;
    // exclusive scan of partition aligned totals (P <= 256)
    int v = (t < P) ? partTot8[t] : 0;
    s[t] = v;
    __syncthreads();
    for (int off = 1; off < 256; off <<= 1) {
        int u = (t >= off) ? s[t - off] : 0;
        __syncthreads();
        s[t] += u;
        __syncthreads();
    }
    int b8 = s[p] - partTot8[p];        // exclusive at p
    int endP = s[p];                    // exclusive at p+1
    if (p == 0 && t == 0) rowptr[N] = s[P - 1];   // grand total
    int lo = p << 9, span = min(N - lo, 512);
    for (int i = t; i < span; i += 256) {
        int r = rowptr[lo + i] + b8;
        srow[i] = r;
        cur[i] = r;
        sdi[i] = dinv[lo + i];
        rowptr[lo + i] = r;             // write back fixed value for gather
    }
    if (t == 0) srow[span] = endP;
    __syncthreads();
    int eBeg = pbase[p], eEnd = pbase[p + 1];
    for (int j = eBeg + t; j < eEnd; j += 256) {
        unsigned int vv = binned[j];
        int sr = (int)(vv >> 9);
        int dl = (int)(vv & 511u);
        int pos = atomicAdd(&cur[dl], 1);
        csrw[pos] = make_float2(__int_as_float(sr << 7), dinv[sr] * sdi[dl]);
    }
    __syncthreads();
    for (int i = t; i < span; i += 256) {
        int c = cur[i];                 // rowfixed + real deg
        float d = sdi[i];
        csrw[c] = make_float2(__int_as_float((lo + i) << 7), d * d);  // self loop
        int nxt = srow[i + 1];
        for (int k = c + 1; k < nxt; ++k)
            csrw[k] = make_float2(0.f, 0.f);                          // pads
    }
}

// MFMA GEMM v3: H[N,64](bf16) = X[N,FIN] @ W[FIN,64].  D = A*B with A=Wt
// (M=ofeat, K), B=X^T (K, N=node). One wave = 16 nodes x 64 ofeats.
// X tile staged through LDS (coalesced global loads, fp32->bf16 in staging);
// B-fragments via ds_read_b128 from padded rows (LDP = FIN+8 halves).
template <int FIN, bool F32IN>
__global__ __launch_bounds__(256) void gemm_mfma_kernel(const void* __restrict__ Xv,
                                                        const unsigned short* __restrict__ Wt,
                                                        unsigned short* __restrict__ H,
                                                        int N) {
    constexpr int KS = FIN / 32;
    constexpr int LDP = FIN + 8;
    __shared__ unsigned short sX[64 * LDP];
    int tid = threadIdx.x;
    int rowBase = blockIdx.x * 64;

    if (F32IN) {
        for (int i = tid * 4; i < 64 * FIN; i += 1024) {
            int r = i / FIN, c = i - r * FIN;
            int gr = min(rowBase + r, N - 1);
            float4 vv = *(const float4*)((const float*)Xv + (size_t)gr * FIN + c);
            unsigned e0 = __float_as_uint(vv.x) + 0x8000u, e1 = __float_as_uint(vv.y) + 0x8000u;
            unsigned e2 = __float_as_uint(vv.z) + 0x8000u, e3 = __float_as_uint(vv.w) + 0x8000u;
            uint2 pk;
            pk.x = __builtin_amdgcn_perm(e1, e0, 0x07060302);
            pk.y = __builtin_amdgcn_perm(e3, e2, 0x07060302);
            *(uint2*)&sX[r * LDP + c] = pk;
        }
    } else {
        for (int i = tid * 8; i < 64 * FIN; i += 2048) {
            int r = i / FIN, c = i - r * FIN;
            int gr = min(rowBase + r, N - 1);
            uint4 vv = *(const uint4*)((const unsigned short*)Xv + (size_t)gr * FIN + c);
            *(uint4*)&sX[r * LDP + c] = vv;
        }
    }
    __syncthreads();

    int wave = tid >> 6;
    int lane = tid & 63;
    int r = lane & 15, g = lane >> 4;
    int node = rowBase + wave * 16 + r;

    bf16x8 afr[4][KS];
#pragma unroll
    for (int m = 0; m < 4; ++m)
#pragma unroll
        for (int s = 0; s < KS; ++s)
            afr[m][s] = *(const bf16x8*)&Wt[(m * 16 + r) * FIN + s * 32 + g * 8];

    f32x4 acc[4];
#pragma unroll
    for (int m = 0; m < 4; ++m) acc[m] = (f32x4){0.f, 0.f, 0.f, 0.f};

#pragma unroll
    for (int s = 0; s < KS; ++s) {
        bf16x8 bfr = *(const bf16x8*)&sX[(wave * 16 + r) * LDP + s * 32 + g * 8];
#pragma unroll
        for (int m = 0; m < 4; ++m)
            acc[m] = __builtin_amdgcn_mfma_f32_16x16x32_bf16(afr[m][s], bfr, acc[m], 0, 0, 0);
    }

    if (node < N) {
#pragma unroll
        for (int m = 0; m < 4; ++m) {
            ushort4 o;
            o.x = f2bf(acc[m][0]); o.y = f2bf(acc[m][1]);
            o.z = f2bf(acc[m][2]); o.w = f2bf(acc[m][3]);
            *(ushort4*)&H[(size_t)node * 64 + m * 16 + g * 4] = o;
        }
    }
}

// Gather step: NQ x 8 edges, unguarded (CSR 8-aligned, pads weight 0).
// All csrw loads issued, then all row loads, then packed-f32 FMAs.
template <int NQ>
__device__ __forceinline__ void gstep(const float2* __restrict__ csrw,
                                      const char* __restrict__ hb,
                                      int e, int g, int fo, f32x2 acc[4]) {
    float2 c[NQ];
#pragma unroll
    for (int q = 0; q < NQ; ++q) c[q] = csrw[e + 8 * q + g];
    uint4 u[NQ];
#pragma unroll
    for (int q = 0; q < NQ; ++q)
        u[q] = *(const uint4*)(hb + __float_as_int(c[q].x) + fo);
#pragma unroll
    for (int q = 0; q < NQ; ++q) {
        f32x2 w2;
        w2.x = c[q].y; w2.y = c[q].y;
        acc[0] = __builtin_elementwise_fma(w2, (f32x2){bflo(u[q].x), bfhi(u[q].x)}, acc[0]);
        acc[1] = __builtin_elementwise_fma(w2, (f32x2){bflo(u[q].y), bfhi(u[q].y)}, acc[1]);
        acc[2] = __builtin_elementwise_fma(w2, (f32x2){bflo(u[q].z), bfhi(u[q].z)}, acc[2]);
        acc[3] = __builtin_elementwise_fma(w2, (f32x2){bflo(u[q].w), bfhi(u[q].w)}, acc[3]);
    }
}

// Gather v8: one wave per dst node. lane j: edge-slot g=j>>3, feat f=j&7.
// CSR 8-aligned incl. self loop; pads weight-0 -> NO predication anywhere.
// nb = span>>3 dispatched as ONE merged gstep<nb> (single csrw-wait + row-wait
// per node); while-loop only for rare span>32. shfl_xor 8/16/32 reduce;
// bias+relu epilogue, bf16 store.
__global__ __launch_bounds__(256) void gather_kernel(const float2* __restrict__ csrw,
                                                     const int* __restrict__ rowptr,
                                                     const unsigned short* __restrict__ h,
                                                     const float* __restrict__ b,
                                                     unsigned short* __restrict__ aggb, int N) {
    int node = (blockIdx.x * 256 + threadIdx.x) >> 6;
    int lane = threadIdx.x & 63;
    if (node >= N) return;
    int g = lane >> 3;
    int f = lane & 7;
    int fo = f * 16;
    int beg = rowptr[node], end = rowptr[node + 1];

    f32x2 acc[4];
#pragma unroll
    for (int k = 0; k < 4; ++k) acc[k] = (f32x2){0.f, 0.f};

    const char* hb = (const char*)h;
    int e = beg;
    int nb = (end - beg) >> 3;
    while (nb > 4) { gstep<4>(csrw, hb, e, g, fo, acc); e += 32; nb -= 4; }
    if (nb == 4)      gstep<4>(csrw, hb, e, g, fo, acc);
    else if (nb == 3) gstep<3>(csrw, hb, e, g, fo, acc);
    else if (nb == 2) gstep<2>(csrw, hb, e, g, fo, acc);
    else              gstep<1>(csrw, hb, e, g, fo, acc);

    float a[8];
#pragma unroll
    for (int k = 0; k < 4; ++k) { a[2 * k] = acc[k].x; a[2 * k + 1] = acc[k].y; }
#pragma unroll
    for (int k = 0; k < 8; ++k) {
        float v = a[k];
        v += __shfl_xor(v, 8);
        v += __shfl_xor(v, 16);
        v += __shfl_xor(v, 32);
        a[k] = v;
    }
    if (g == 0) {
        float4 bv0 = *(const float4*)&b[f * 8];
        float4 bv1 = *(const float4*)&b[f * 8 + 4];
        float a0 = fmaxf(a[0] + bv0.x, 0.f), a1 = fmaxf(a[1] + bv0.y, 0.f);
        float a2 = fmaxf(a[2] + bv0.z, 0.f), a3 = fmaxf(a[3] + bv0.w, 0.f);
        float a4 = fmaxf(a[4] + bv1.x, 0.f), a5 = fmaxf(a[5] + bv1.y, 0.f);
        float a6 = fmaxf(a[6] + bv1.z, 0.f), a7 = fmaxf(a[7] + bv1.w, 0.f);
        uint4 o;
        o.x = ((unsigned)f2bf(a1) << 16) | f2bf(a0);
        o.y = ((unsigned)f2bf(a3) << 16) | f2bf(a2);
        o.z = ((unsigned)f2bf(a5) << 16) | f2bf(a4);
        o.w = ((unsigned)f2bf(a7) << 16) | f2bf(a6);
        *(uint4*)&aggb[((size_t)node << 6) + f * 8] = o;
    }
}

// Pool v2: one wave per 32 contiguous nodes (lane = col). batch preloaded once
// (coalesced) + __shfl per node; all 32 row loads (128B each, 4KB contiguous
// per wave) issued upfront; wave-uniform flush on graph change.
__global__ __launch_bounds__(256) void pool_kernel(const unsigned short* __restrict__ hb,
                                                   const int* __restrict__ batch,
                                                   float* __restrict__ sums,
                                                   float* __restrict__ cnts, int N) {
    int lane = threadIdx.x & 63;
    int wid = (blockIdx.x * 256 + threadIdx.x) >> 6;
    int base = wid * 32;
    if (base >= N) return;
    int nn = min(N - base, 32);
    int bl = batch[base + min(lane & 31, nn - 1)];

    float v[32];
#pragma unroll
    for (int j = 0; j < 32; ++j) {
        int node = base + min(j, nn - 1);
        v[j] = bf2f(hb[(size_t)node * 64 + lane]);
    }

    int curg = __shfl(bl, 0);
    float acc = 0.f, cnt = 0.f;
#pragma unroll
    for (int j = 0; j < 32; ++j) {
        if (j < nn) {
            int g = __shfl(bl, j);
            if (g != curg) {
                atomicAdd(&sums[curg * 64 + lane], acc);
                if (lane == 0) atomicAdd(&cnts[curg], cnt);
                acc = 0.f; cnt = 0.f; curg = g;
            }
            acc += v[j]; cnt += 1.f;
        }
    }
    atomicAdd(&sums[curg * 64 + lane], acc);
    if (lane == 0) atomicAdd(&cnts[curg], cnt);
}

// One thread per graph: pooled = sums/cnt, logits = pooled @ Wl + bl, softmax.
__global__ void final_kernel(const float* __restrict__ sums, const float* __restrict__ cnts,
                             const float* __restrict__ Wl, const float* __restrict__ bl,
                             float* __restrict__ out, int G) {
    int g = blockIdx.x * blockDim.x + threadIdx.x;
    if (g >= G) return;
    float inv = 1.0f / fmaxf(cnts[g], 1.0f);
    float logits[10];
#pragma unroll
    for (int k = 0; k < 10; ++k) logits[k] = bl[k];
    for (int c = 0; c < 64; ++c) {
        float p = sums[g * 64 + c] * inv;
#pragma unroll
        for (int k = 0; k < 10; ++k) logits[k] = fmaf(p, Wl[c * 10 + k], logits[k]);
    }
    float m = logits[0];
#pragma unroll
    for (int k = 1; k < 10; ++k) m = fmaxf(m, logits[k]);
    float se = 0.f;
#pragma unroll
    for (int k = 0; k < 10; ++k) { logits[k] = expf(logits[k] - m); se += logits[k]; }
    float is = 1.0f / se;
#pragma unroll
    for (int k = 0; k < 10; ++k) out[g * 10 + k] = logits[k] * is;
}

extern "C" void kernel_launch(void* const* d_in, const int* in_sizes, int n_in,
                              void* d_out, int out_size, void* d_ws, size_t ws_size,
                              hipStream_t stream) {
    const float* x    = (const float*)d_in[0];
    const int* edges  = (const int*)d_in[1];
    const int* batch  = (const int*)d_in[2];
    const float* W1   = (const float*)d_in[3];
    const float* b1   = (const float*)d_in[4];
    const float* W2   = (const float*)d_in[5];
    const float* b2   = (const float*)d_in[6];
    const float* W3   = (const float*)d_in[7];
    const float* b3   = (const float*)d_in[8];
    const float* Wl   = (const float*)d_in[9];
    const float* bl   = (const float*)d_in[10];

    const int N = in_sizes[0] / 128;   // 100000
    const int E = in_sizes[1] / 2;     // 1600000
    const int G = out_size / 10;       // 64
    const int* src = edges;
    const int* dst = edges + E;

    // workspace layout (floats). csrw sized for worst-case padding E + 8N.
    float* ws     = (float*)d_ws;
    unsigned short* h = (unsigned short*)ws;              // N*64 bf16 (slot: N*64 floats)
    unsigned short* aggb = (unsigned short*)(ws + (size_t)N * 64);  // N*64 bf16
    unsigned int* binned = (unsigned int*)ws;             // E uint, ALIASES h (dead before gemm1)
    size_t csrwOff = (size_t)2 * N * 64;
    float2* csrw  = (float2*)(ws + csrwOff);              // (E+8N) float2
    size_t o = csrwOff + (size_t)2 * (E + 8 * N);
    float* dinv   = ws + o;            o += N;            // N
    int*   rowptr = (int*)(ws + o);    o += N + 1;        // N+1
    int*   counts = (int*)(ws + o);    o += 256 * 256;
    int*   offs   = (int*)(ws + o);    o += 256 * 256;
    int*   pbase  = (int*)(ws + o);    o += 257;
    float* sums   = ws + o;            o += (size_t)G * 64;
    float* cnts   = ws + o;            o += G;
    int*   partTot8 = (int*)(ws + o);  o += 256;
    unsigned short* Wt1 = (unsigned short*)(ws + o);      // 64*128 + 2*64*64 shorts
    unsigned short* Wt2 = Wt1 + 64 * 128;
    unsigned short* Wt3 = Wt2 + 64 * 64;

    const int gemmGrid = (N + 63) / 64;
    const int gatherGrid = (N + 3) / 4;
    const int poolGrid = ((N + 31) / 32 + 3) / 4;
    const int P = (N + 511) >> 9;                 // 196 partitions of 512 nodes
    const int C = (E + 255) / 256;                // edges per chunk (256 chunks)

    // sort -> padded CSR {src_byte_off, w} with self-loops + weight-0 pads
    hist_kernel<<<260, 256, 0, stream>>>(dst, counts, E, P, C,
                                         W1, W2, W3, Wt1, Wt2, Wt3, sums, G);
    pscan_kernel<<<1, 256, 0, stream>>>(counts, pbase, P);
    offs_kernel<<<P, 256, 0, stream>>>(counts, pbase, offs);
    bin_kernel<<<256, 256, 0, stream>>>(src, dst, offs, binned, E, P, C);
    lsortA_kernel<<<P, 512, 0, stream>>>(binned, pbase, rowptr, dinv, partTot8, N);
    lsortB_kernel<<<P, 256, 0, stream>>>(binned, pbase, partTot8, rowptr, dinv, csrw, N, P);

    // layer 1: x[N,128] @ W1 -> h bf16 (overwrites binned; build complete); gather
    gemm_mfma_kernel<128, true><<<gemmGrid, 256, 0, stream>>>(x, Wt1, h, N);
    gather_kernel<<<gatherGrid, 256, 0, stream>>>(csrw, rowptr, h, b1, aggb, N);

    // layer 2
    gemm_mfma_kernel<64, false><<<gemmGrid, 256, 0, stream>>>(aggb, Wt2, h, N);
    gather_kernel<<<gatherGrid, 256, 0, stream>>>(csrw, rowptr, h, b2, aggb, N);

    // layer 3
    gemm_mfma_kernel<64, false><<<gemmGrid, 256, 0, stream>>>(aggb, Wt3, h, N);
    gather_kernel<<<gatherGrid, 256, 0, stream>>>(csrw, rowptr, h, b3, aggb, N);

    // mean-pool per graph + head + softmax (sums/cnts zeroed in hist's extra block)
    pool_kernel<<<poolGrid, 256, 0, stream>>>(aggb, batch, sums, cnts, N);
    final_kernel<<<1, 64, 0, stream>>>(sums, cnts, Wl, bl, (float*)d_out, G);
}

// Round 6
// 346.918 us; speedup vs baseline: 1.3192x; 1.0341x over previous
//
#include <hip/hip_runtime.h>
#include <math.h>

// GCN via CSR gather. CSR(dst) built with a two-level binned counting sort where
// node degrees are derived INSIDE the partition sort (lsortA LDS histogram).
// 3x (MFMA GEMM -> gather-agg[+relu,bf16]) -> mean-pool -> head -> softmax.
//
// NOTE (round 5 counters): top-5 = __amd_rocclr_fillBufferAligned x4/iter,
// 41us each, 256MiB at 81% HBM peak = harness workspace re-poison, counted in
// dur_us, already at roofline -> ~165us fixed tax. Addressable budget ~195us.
//
// Gather v9 (this round): v8 still had a 3-hop dependent chain per wave
// (rowptr load -> csrw load -> row loads) + nb branch ladder. CSR is now
// FIXED-STRIDE: 24 main slots per node at csrw[node*24] (deg<=23 = 96.3% of
// Poisson(16), self-loop included, weight-0 pads), overflow (deg>=24, 3.7%)
// in an 8-aligned side region addressed by packed ovfw[node] = base/8|groups.
// beg = node*24 is pure VALU -> csrw loads issue at cycle 0; rowptr deleted;
// straight gstep<3>, ovf branch off critical path. Build: ovf bases are
// per-partition fixed stride (align8(pbase[p]) + 4096p; capacity proof:
// sum(ovfUsed+7) <= edges_p + 3584 < 4096) -> partTot8 cross-scan deleted.
//
// Gather v8 (round 5): merged remainder gstep<nb> (one csrw-wait + one
// row-wait), f32x2 pk_fma. Pool v2 (round 4): wave/32 nodes, batch __shfl,
// 32 row loads upfront. GEMM v3 (round 4): LDS-staged X, MFMA 16x16x32.
// Gather v7 (round 3): 8-aligned padded CSR, no predication. v6 (round 1):
// lane j=(edge g, feat16B f), dwordx4 row loads. 64.4->47.5->45.2->42.9->~38us.
// N=100000 nodes, E=1.6M edges, nhid=64, Poisson(16) degrees.

typedef __attribute__((ext_vector_type(8))) short bf16x8;
typedef __attribute__((ext_vector_type(4))) float f32x4;
typedef __attribute__((ext_vector_type(2))) float f32x2;

__device__ __forceinline__ unsigned short f2bf(float f) {
    unsigned int u = __float_as_uint(f);
    u += 0x7fffu + ((u >> 16) & 1u);   // round-to-nearest-even
    return (unsigned short)(u >> 16);
}
__device__ __forceinline__ float bf2f(unsigned short u) {
    return __uint_as_float((unsigned int)u << 16);
}
__device__ __forceinline__ float bflo(unsigned int u) {
    return __uint_as_float(u << 16);
}
__device__ __forceinline__ float bfhi(unsigned int u) {
    return __uint_as_float(u & 0xffff0000u);
}

// ---- binned counting sort: partition = dst>>9 (512 nodes), P<=256, 256 chunks ----
// hist fused: blocks 256..258 = W->Wt bf16 transpose; block 259 = zero sums/cnts.

__global__ __launch_bounds__(256) void hist_kernel(const int* __restrict__ dst,
                                                   int* __restrict__ counts,
                                                   int E, int P, int C,
                                                   const float* __restrict__ W1,
                                                   const float* __restrict__ W2,
                                                   const float* __restrict__ W3,
                                                   unsigned short* __restrict__ Wt1,
                                                   unsigned short* __restrict__ Wt2,
                                                   unsigned short* __restrict__ Wt3,
                                                   float* __restrict__ sums, int G) {
    int t = threadIdx.x, b = blockIdx.x;
    if (b >= 256) {
        int xb = b - 256;
        if (xb < 3) {           // prepw
            const float* W = (xb == 0) ? W1 : ((xb == 1) ? W2 : W3);
            unsigned short* Wt = (xb == 0) ? Wt1 : ((xb == 1) ? Wt2 : Wt3);
            int K = (xb == 0) ? 128 : 64;
            int o = t & 63;
            for (int k = t >> 6; k < K; k += 4)
                Wt[o * K + k] = f2bf(W[k * 64 + o]);
        } else {                // zero sums+cnts (G*65 floats)
            for (int i = t; i < G * 65; i += 256) sums[i] = 0.f;
        }
        return;
    }
    __shared__ int hist[256];
    if (t < P) hist[t] = 0;
    __syncthreads();
    int beg = b * C, end = min(E, beg + C);
    for (int e = beg + t; e < end; e += 256)
        atomicAdd(&hist[dst[e] >> 9], 1);
    __syncthreads();
    if (t < P) counts[t * 256 + b] = hist[t];
}

__global__ __launch_bounds__(256) void pscan_kernel(const int* __restrict__ counts,
                                                    int* __restrict__ pbase,
                                                    int P) {
    __shared__ int s[256];
    int t = threadIdx.x;
    int v = 0;
    if (t < P)
        for (int b = 0; b < 256; ++b) v += counts[t * 256 + b];
    s[t] = v;
    __syncthreads();
    for (int off = 1; off < 256; off <<= 1) {
        int u = (t >= off) ? s[t - off] : 0;
        __syncthreads();
        s[t] += u;
        __syncthreads();
    }
    if (t < P) pbase[t] = s[t] - v;
    if (t == 255) pbase[P] = s[255];
}

__global__ __launch_bounds__(256) void offs_kernel(const int* __restrict__ counts,
                                                   const int* __restrict__ pbase,
                                                   int* __restrict__ offs) {
    __shared__ int s[256];
    int t = threadIdx.x, p = blockIdx.x;
    int v = counts[p * 256 + t];
    s[t] = v;
    __syncthreads();
    for (int off = 1; off < 256; off <<= 1) {
        int u = (t >= off) ? s[t - off] : 0;
        __syncthreads();
        s[t] += u;
        __syncthreads();
    }
    offs[p * 256 + t] = pbase[p] + s[t] - v;
}

__global__ __launch_bounds__(256) void bin_kernel(const int* __restrict__ src,
                                                  const int* __restrict__ dst,
                                                  const int* __restrict__ offs,
                                                  unsigned int* __restrict__ binned,
                                                  int E, int P, int C) {
    __shared__ int cur[256];
    int t = threadIdx.x, b = blockIdx.x;
    if (t < P) cur[t] = offs[t * 256 + b];
    __syncthreads();
    int beg = b * C, end = min(E, beg + C);
    for (int e = beg + t; e < end; e += 256) {
        int d = dst[e], s = src[e];
        int pos = atomicAdd(&cur[d >> 9], 1);
        binned[pos] = ((unsigned int)s << 9) | (unsigned int)(d & 511);
    }
}

// Per-node degree (LDS histogram) -> dinv + overflow allocation. Overflow region
// for node with deg1 = deg+1 > 24: gsl = align8(deg1-24) slots, allocated at
// per-partition fixed base align8(pbase[p]) + 4096p + localScan. ovfw[node] =
// (slotBase/8)<<7 | (gsl/8), or 0 if no overflow. NO cross-partition scan.
__global__ __launch_bounds__(512) void lsortA_kernel(const unsigned int* __restrict__ binned,
                                                     const int* __restrict__ pbase,
                                                     float* __restrict__ dinv,
                                                     int* __restrict__ ovfw, int N) {
    __shared__ int ldeg[512];
    __shared__ int s[512];
    int t = threadIdx.x, p = blockIdx.x;
    int lo = p << 9;
    ldeg[t] = 0;
    __syncthreads();
    int eBeg = pbase[p], eEnd = pbase[p + 1];
    for (int j = eBeg + t; j < eEnd; j += 512)
        atomicAdd(&ldeg[binned[j] & 511u], 1);
    __syncthreads();
    int real = ldeg[t];
    int deg1 = real + 1;
    int ovfUsed = (lo + t < N) ? max(deg1 - 24, 0) : 0;
    int gsl = ((ovfUsed + 7) >> 3) << 3;       // padded ovf slots (multiple of 8)
    s[t] = gsl;
    __syncthreads();
    for (int off = 1; off < 512; off <<= 1) {
        int u = (t >= off) ? s[t - off] : 0;
        __syncthreads();
        s[t] += u;
        __syncthreads();
    }
    if (lo + t < N) {
        dinv[lo + t] = rsqrtf((float)deg1);
        int obase = ((eBeg + 7) & ~7) + (p << 12);       // align8(pbase[p]) + 4096p
        int base = obase + (s[t] - gsl);                 // exclusive local scan
        ovfw[lo + t] = gsl ? (((base >> 3) << 7) | (gsl >> 3)) : 0;
    }
}

// Scatter: entry i (arrival order; self appended last) -> i<24: csrw[node*24+i],
// else ovf[base + i-24]. Then pads {0,0} in main tail and ovf tail.
__global__ __launch_bounds__(256) void lsortB_kernel(const unsigned int* __restrict__ binned,
                                                     const int* __restrict__ pbase,
                                                     const int* __restrict__ ovfw,
                                                     const float* __restrict__ dinv,
                                                     float2* __restrict__ csrw,
                                                     float2* __restrict__ ovf, int N) {
    __shared__ int cur[512];
    __shared__ float sdi[512];
    __shared__ int sov[512];
    int t = threadIdx.x, p = blockIdx.x;
    int lo = p << 9, span = min(N - lo, 512);
    for (int i = t; i < span; i += 256) {
        cur[i] = 0;
        sdi[i] = dinv[lo + i];
        sov[i] = ovfw[lo + i];
    }
    __syncthreads();
    int eBeg = pbase[p], eEnd = pbase[p + 1];
    for (int j = eBeg + t; j < eEnd; j += 256) {
        unsigned int vv = binned[j];
        int sr = (int)(vv >> 9);
        int dl = (int)(vv & 511u);
        int i = atomicAdd(&cur[dl], 1);
        float2 ent = make_float2(__int_as_float(sr << 7), dinv[sr] * sdi[dl]);
        if (i < 24) csrw[(size_t)(lo + dl) * 24 + i] = ent;
        else        ovf[(size_t)((sov[dl] >> 7) << 3) + i - 24] = ent;
    }
    __syncthreads();
    for (int i = t; i < span; i += 256) {
        int real = cur[i];
        int node = lo + i;
        float d = sdi[i];
        float2 self = make_float2(__int_as_float(node << 7), d * d);
        int deg1 = real + 1;
        int ob = (sov[i] >> 7) << 3;
        if (real < 24) csrw[(size_t)node * 24 + real] = self;
        else           ovf[(size_t)ob + real - 24] = self;
        for (int k = deg1; k < 24; ++k)
            csrw[(size_t)node * 24 + k] = make_float2(0.f, 0.f);     // main pads
        int gsl = (sov[i] & 127) << 3;
        for (int k = max(deg1 - 24, 0); k < gsl; ++k)
            ovf[(size_t)ob + k] = make_float2(0.f, 0.f);             // ovf pads
    }
}

// MFMA GEMM v3: H[N,64](bf16) = X[N,FIN] @ W[FIN,64].  D = A*B with A=Wt
// (M=ofeat, K), B=X^T (K, N=node). One wave = 16 nodes x 64 ofeats.
// X tile staged through LDS (coalesced global loads, fp32->bf16 in staging);
// B-fragments via ds_read_b128 from padded rows (LDP = FIN+8 halves).
template <int FIN, bool F32IN>
__global__ __launch_bounds__(256) void gemm_mfma_kernel(const void* __restrict__ Xv,
                                                        const unsigned short* __restrict__ Wt,
                                                        unsigned short* __restrict__ H,
                                                        int N) {
    constexpr int KS = FIN / 32;
    constexpr int LDP = FIN + 8;
    __shared__ unsigned short sX[64 * LDP];
    int tid = threadIdx.x;
    int rowBase = blockIdx.x * 64;

    if (F32IN) {
        for (int i = tid * 4; i < 64 * FIN; i += 1024) {
            int r = i / FIN, c = i - r * FIN;
            int gr = min(rowBase + r, N - 1);
            float4 vv = *(const float4*)((const float*)Xv + (size_t)gr * FIN + c);
            unsigned e0 = __float_as_uint(vv.x) + 0x8000u, e1 = __float_as_uint(vv.y) + 0x8000u;
            unsigned e2 = __float_as_uint(vv.z) + 0x8000u, e3 = __float_as_uint(vv.w) + 0x8000u;
            uint2 pk;
            pk.x = __builtin_amdgcn_perm(e1, e0, 0x07060302);
            pk.y = __builtin_amdgcn_perm(e3, e2, 0x07060302);
            *(uint2*)&sX[r * LDP + c] = pk;
        }
    } else {
        for (int i = tid * 8; i < 64 * FIN; i += 2048) {
            int r = i / FIN, c = i - r * FIN;
            int gr = min(rowBase + r, N - 1);
            uint4 vv = *(const uint4*)((const unsigned short*)Xv + (size_t)gr * FIN + c);
            *(uint4*)&sX[r * LDP + c] = vv;
        }
    }
    __syncthreads();

    int wave = tid >> 6;
    int lane = tid & 63;
    int r = lane & 15, g = lane >> 4;
    int node = rowBase + wave * 16 + r;

    bf16x8 afr[4][KS];
#pragma unroll
    for (int m = 0; m < 4; ++m)
#pragma unroll
        for (int s = 0; s < KS; ++s)
            afr[m][s] = *(const bf16x8*)&Wt[(m * 16 + r) * FIN + s * 32 + g * 8];

    f32x4 acc[4];
#pragma unroll
    for (int m = 0; m < 4; ++m) acc[m] = (f32x4){0.f, 0.f, 0.f, 0.f};

#pragma unroll
    for (int s = 0; s < KS; ++s) {
        bf16x8 bfr = *(const bf16x8*)&sX[(wave * 16 + r) * LDP + s * 32 + g * 8];
#pragma unroll
        for (int m = 0; m < 4; ++m)
            acc[m] = __builtin_amdgcn_mfma_f32_16x16x32_bf16(afr[m][s], bfr, acc[m], 0, 0, 0);
    }

    if (node < N) {
#pragma unroll
        for (int m = 0; m < 4; ++m) {
            ushort4 o;
            o.x = f2bf(acc[m][0]); o.y = f2bf(acc[m][1]);
            o.z = f2bf(acc[m][2]); o.w = f2bf(acc[m][3]);
            *(ushort4*)&H[(size_t)node * 64 + m * 16 + g * 4] = o;
        }
    }
}

// Gather step: NQ x 8 edges, unguarded (slots 8-aligned, pads weight 0).
// All csrw loads issued, then all row loads, then packed-f32 FMAs.
template <int NQ>
__device__ __forceinline__ void gstep(const float2* __restrict__ csrw,
                                      const char* __restrict__ hb,
                                      int e, int g, int fo, f32x2 acc[4]) {
    float2 c[NQ];
#pragma unroll
    for (int q = 0; q < NQ; ++q) c[q] = csrw[e + 8 * q + g];
    uint4 u[NQ];
#pragma unroll
    for (int q = 0; q < NQ; ++q)
        u[q] = *(const uint4*)(hb + __float_as_int(c[q].x) + fo);
#pragma unroll
    for (int q = 0; q < NQ; ++q) {
        f32x2 w2;
        w2.x = c[q].y; w2.y = c[q].y;
        acc[0] = __builtin_elementwise_fma(w2, (f32x2){bflo(u[q].x), bfhi(u[q].x)}, acc[0]);
        acc[1] = __builtin_elementwise_fma(w2, (f32x2){bflo(u[q].y), bfhi(u[q].y)}, acc[1]);
        acc[2] = __builtin_elementwise_fma(w2, (f32x2){bflo(u[q].z), bfhi(u[q].z)}, acc[2]);
        acc[3] = __builtin_elementwise_fma(w2, (f32x2){bflo(u[q].w), bfhi(u[q].w)}, acc[3]);
    }
}

// Gather v9: one wave per dst node. lane j: edge-slot g=j>>3, feat f=j&7.
// Fixed-stride CSR: 24 slots at csrw[node*24] (self-loop included, weight-0
// pads) -> beg is pure VALU, csrw loads issue at cycle 0, NO rowptr, NO nb
// branch: straight gstep<3>. Overflow (deg>=24, 3.7%): packed ovfw[node] ->
// 8-aligned groups in ovf region, rare branch off the critical path.
// shfl_xor 8/16/32 reduce; bias+relu epilogue, bf16 store.
__global__ __launch_bounds__(256) void gather_kernel(const float2* __restrict__ csrw,
                                                     const float2* __restrict__ ovf,
                                                     const int* __restrict__ ovfw,
                                                     const unsigned short* __restrict__ h,
                                                     const float* __restrict__ b,
                                                     unsigned short* __restrict__ aggb, int N) {
    int node = (blockIdx.x * 256 + threadIdx.x) >> 6;
    int lane = threadIdx.x & 63;
    if (node >= N) return;
    int g = lane >> 3;
    int f = lane & 7;
    int fo = f * 16;

    f32x2 acc[4];
#pragma unroll
    for (int k = 0; k < 4; ++k) acc[k] = (f32x2){0.f, 0.f};

    const char* hb = (const char*)h;
    gstep<3>(csrw, hb, node * 24, g, fo, acc);

    int ow = ovfw[node];
    if (ow) {
        int onb = ow & 127;
        int oe = (ow >> 7) << 3;
        while (onb >= 4) { gstep<4>(ovf, hb, oe, g, fo, acc); oe += 32; onb -= 4; }
        if (onb == 3)      gstep<3>(ovf, hb, oe, g, fo, acc);
        else if (onb == 2) gstep<2>(ovf, hb, oe, g, fo, acc);
        else if (onb == 1) gstep<1>(ovf, hb, oe, g, fo, acc);
    }

    float a[8];
#pragma unroll
    for (int k = 0; k < 4; ++k) { a[2 * k] = acc[k].x; a[2 * k + 1] = acc[k].y; }
#pragma unroll
    for (int k = 0; k < 8; ++k) {
        float v = a[k];
        v += __shfl_xor(v, 8);
        v += __shfl_xor(v, 16);
        v += __shfl_xor(v, 32);
        a[k] = v;
    }
    if (g == 0) {
        float4 bv0 = *(const float4*)&b[f * 8];
        float4 bv1 = *(const float4*)&b[f * 8 + 4];
        float a0 = fmaxf(a[0] + bv0.x, 0.f), a1 = fmaxf(a[1] + bv0.y, 0.f);
        float a2 = fmaxf(a[2] + bv0.z, 0.f), a3 = fmaxf(a[3] + bv0.w, 0.f);
        float a4 = fmaxf(a[4] + bv1.x, 0.f), a5 = fmaxf(a[5] + bv1.y, 0.f);
        float a6 = fmaxf(a[6] + bv1.z, 0.f), a7 = fmaxf(a[7] + bv1.w, 0.f);
        uint4 o;
        o.x = ((unsigned)f2bf(a1) << 16) | f2bf(a0);
        o.y = ((unsigned)f2bf(a3) << 16) | f2bf(a2);
        o.z = ((unsigned)f2bf(a5) << 16) | f2bf(a4);
        o.w = ((unsigned)f2bf(a7) << 16) | f2bf(a6);
        *(uint4*)&aggb[((size_t)node << 6) + f * 8] = o;
    }
}

// Pool v2: one wave per 32 contiguous nodes (lane = col). batch preloaded once
// (coalesced) + __shfl per node; all 32 row loads (128B each, 4KB contiguous
// per wave) issued upfront; wave-uniform flush on graph change.
__global__ __launch_bounds__(256) void pool_kernel(const unsigned short* __restrict__ hb,
                                                   const int* __restrict__ batch,
                                                   float* __restrict__ sums,
                                                   float* __restrict__ cnts, int N) {
    int lane = threadIdx.x & 63;
    int wid = (blockIdx.x * 256 + threadIdx.x) >> 6;
    int base = wid * 32;
    if (base >= N) return;
    int nn = min(N - base, 32);
    int bl = batch[base + min(lane & 31, nn - 1)];

    float v[32];
#pragma unroll
    for (int j = 0; j < 32; ++j) {
        int node = base + min(j, nn - 1);
        v[j] = bf2f(hb[(size_t)node * 64 + lane]);
    }

    int curg = __shfl(bl, 0);
    float acc = 0.f, cnt = 0.f;
#pragma unroll
    for (int j = 0; j < 32; ++j) {
        if (j < nn) {
            int g = __shfl(bl, j);
            if (g != curg) {
                atomicAdd(&sums[curg * 64 + lane], acc);
                if (lane == 0) atomicAdd(&cnts[curg], cnt);
                acc = 0.f; cnt = 0.f; curg = g;
            }
            acc += v[j]; cnt += 1.f;
        }
    }
    atomicAdd(&sums[curg * 64 + lane], acc);
    if (lane == 0) atomicAdd(&cnts[curg], cnt);
}

// One thread per graph: pooled = sums/cnt, logits = pooled @ Wl + bl, softmax.
__global__ void final_kernel(const float* __restrict__ sums, const float* __restrict__ cnts,
                             const float* __restrict__ Wl, const float* __restrict__ bl,
                             float* __restrict__ out, int G) {
    int g = blockIdx.x * blockDim.x + threadIdx.x;
    if (g >= G) return;
    float inv = 1.0f / fmaxf(cnts[g], 1.0f);
    float logits[10];
#pragma unroll
    for (int k = 0; k < 10; ++k) logits[k] = bl[k];
    for (int c = 0; c < 64; ++c) {
        float p = sums[g * 64 + c] * inv;
#pragma unroll
        for (int k = 0; k < 10; ++k) logits[k] = fmaf(p, Wl[c * 10 + k], logits[k]);
    }
    float m = logits[0];
#pragma unroll
    for (int k = 1; k < 10; ++k) m = fmaxf(m, logits[k]);
    float se = 0.f;
#pragma unroll
    for (int k = 0; k < 10; ++k) { logits[k] = expf(logits[k] - m); se += logits[k]; }
    float is = 1.0f / se;
#pragma unroll
    for (int k = 0; k < 10; ++k) out[g * 10 + k] = logits[k] * is;
}

extern "C" void kernel_launch(void* const* d_in, const int* in_sizes, int n_in,
                              void* d_out, int out_size, void* d_ws, size_t ws_size,
                              hipStream_t stream) {
    const float* x    = (const float*)d_in[0];
    const int* edges  = (const int*)d_in[1];
    const int* batch  = (const int*)d_in[2];
    const float* W1   = (const float*)d_in[3];
    const float* b1   = (const float*)d_in[4];
    const float* W2   = (const float*)d_in[5];
    const float* b2   = (const float*)d_in[6];
    const float* W3   = (const float*)d_in[7];
    const float* b3   = (const float*)d_in[8];
    const float* Wl   = (const float*)d_in[9];
    const float* bl   = (const float*)d_in[10];

    const int N = in_sizes[0] / 128;   // 100000
    const int E = in_sizes[1] / 2;     // 1600000
    const int G = out_size / 10;       // 64
    const int* src = edges;
    const int* dst = edges + E;

    // workspace layout (floats).
    float* ws     = (float*)d_ws;
    unsigned short* h = (unsigned short*)ws;              // N*64 bf16 = N*32 floats
    unsigned short* aggb = (unsigned short*)(ws + (size_t)N * 32);  // N*64 bf16
    unsigned int* binned = (unsigned int*)ws;             // E uint, ALIASES h (dead before gemm1)
    size_t o = (size_t)N * 64;
    float2* csrw  = (float2*)(ws + o);  o += (size_t)48 * N;          // 24N float2
    float2* ovf   = (float2*)(ws + o);  o += (size_t)2 * (E + 4096 * 256 + 8);
    float* dinv   = ws + o;            o += N;
    int*   ovfw   = (int*)(ws + o);    o += N;
    int*   counts = (int*)(ws + o);    o += 256 * 256;
    int*   offs   = (int*)(ws + o);    o += 256 * 256;
    int*   pbase  = (int*)(ws + o);    o += 257;
    float* sums   = ws + o;            o += (size_t)G * 64;
    float* cnts   = ws + o;            o += G;
    unsigned short* Wt1 = (unsigned short*)(ws + o);      // 64*128 + 2*64*64 shorts
    unsigned short* Wt2 = Wt1 + 64 * 128;
    unsigned short* Wt3 = Wt2 + 64 * 64;

    const int gemmGrid = (N + 63) / 64;
    const int gatherGrid = (N + 3) / 4;
    const int poolGrid = ((N + 31) / 32 + 3) / 4;
    const int P = (N + 511) >> 9;                 // 196 partitions of 512 nodes
    const int C = (E + 255) / 256;                // edges per chunk (256 chunks)

    // sort -> fixed-stride CSR (24 slots/node) + overflow region
    hist_kernel<<<260, 256, 0, stream>>>(dst, counts, E, P, C,
                                         W1, W2, W3, Wt1, Wt2, Wt3, sums, G);
    pscan_kernel<<<1, 256, 0, stream>>>(counts, pbase, P);
    offs_kernel<<<P, 256, 0, stream>>>(counts, pbase, offs);
    bin_kernel<<<256, 256, 0, stream>>>(src, dst, offs, binned, E, P, C);
    lsortA_kernel<<<P, 512, 0, stream>>>(binned, pbase, dinv, ovfw, N);
    lsortB_kernel<<<P, 256, 0, stream>>>(binned, pbase, ovfw, dinv, csrw, ovf, N);

    // layer 1: x[N,128] @ W1 -> h bf16 (overwrites binned; build complete); gather
    gemm_mfma_kernel<128, true><<<gemmGrid, 256, 0, stream>>>(x, Wt1, h, N);
    gather_kernel<<<gatherGrid, 256, 0, stream>>>(csrw, ovf, ovfw, h, b1, aggb, N);

    // layer 2
    gemm_mfma_kernel<64, false><<<gemmGrid, 256, 0, stream>>>(aggb, Wt2, h, N);
    gather_kernel<<<gatherGrid, 256, 0, stream>>>(csrw, ovf, ovfw, h, b2, aggb, N);

    // layer 3
    gemm_mfma_kernel<64, false><<<gemmGrid, 256, 0, stream>>>(aggb, Wt3, h, N);
    gather_kernel<<<gatherGrid, 256, 0, stream>>>(csrw, ovf, ovfw, h, b3, aggb, N);

    // mean-pool per graph + head + softmax (sums/cnts zeroed in hist's extra block)
    pool_kernel<<<poolGrid, 256, 0, stream>>>(aggb, batch, sums, cnts, N);
    final_kernel<<<1, 64, 0, stream>>>(sums, cnts, Wl, bl, (float*)d_out, G);
}